// Round 1
// baseline (291.449 us; speedup 1.0000x reference)
//
#include <hip/hip_runtime.h>
#include <hip/hip_bf16.h>
#include <stdint.h>

typedef __attribute__((ext_vector_type(8))) short short8;
typedef __attribute__((ext_vector_type(4))) float f32x4;
typedef __attribute__((ext_vector_type(4))) unsigned short ushort4v;

#define NB 32
#define NS 512
#define NE 256
#define NH2 128
#define NG 512
#define NT 22

__device__ __forceinline__ unsigned short f2bf(float f) {
    union { float f; unsigned u; } v; v.f = f;
    unsigned r = v.u + 0x7fffu + ((v.u >> 16) & 1u);
    return (unsigned short)(r >> 16);
}
__device__ __forceinline__ float bf2f(unsigned short b) {
    union { unsigned u; float f; } v; v.u = ((unsigned)b) << 16;
    return v.f;
}
__device__ __forceinline__ float sigmoidf_(float x) {
    return __builtin_amdgcn_rcpf(1.f + __expf(-x));
}
__device__ __forceinline__ float tanhf_(float x) {
    return 1.f - 2.f * __builtin_amdgcn_rcpf(__expf(2.f * x) + 1.f);
}

// ---------------- prep: weight conversions + feats init ----------------
__global__ void k_prep(const float* Wih_f, const float* Wih_b,
                       const float* Whh_f, const float* Whh_b,
                       const float* fcW, const float* fcb,
                       unsigned short* Wb_ih, unsigned short* Wb_hh,
                       unsigned short* fcpad, float* feats)
{
    int idx = blockIdx.x * blockDim.x + threadIdx.x;
    const int n1 = 2 * NG * NE;     // 262144
    const int n2 = 2 * NG * NH2;    // 131072
    const int n3 = 2 * 32 * NH2;    // 8192
    const int n4 = NB * NS * NT;    // 360448
    if (idx < n1) {
        const float* src = (idx < NG * NE) ? Wih_f : Wih_b;
        Wb_ih[idx] = f2bf(src[idx % (NG * NE)]);
    } else if (idx < n1 + n2) {
        int i2 = idx - n1;
        const float* src = (i2 < NG * NH2) ? Whh_f : Whh_b;
        Wb_hh[i2] = f2bf(src[i2 % (NG * NH2)]);
    } else if (idx < n1 + n2 + n3) {
        int i3 = idx - n1 - n2;
        int d = i3 / (32 * NH2);
        int j = (i3 / NH2) % 32;
        int k = i3 % NH2;
        fcpad[i3] = (j < NT) ? f2bf(fcW[j * 256 + d * NH2 + k]) : (unsigned short)0;
    } else if (idx < n1 + n2 + n3 + n4) {
        int i4 = idx - n1 - n2 - n3;
        feats[i4] = fcb[i4 % NT];
    }
}

// ---------------- embedding gather + bf16 convert ----------------
__global__ void k_embcvt(const int* X, const float* emb, unsigned short* ebf)
{
    int r = blockIdx.x;          // 16384 rows
    int lane = threadIdx.x;      // 64
    int xr = X[r];
    f32x4 v = *(const f32x4*)(emb + (size_t)xr * NE + lane * 4);
    ushort4v o;
    o[0] = f2bf(v[0]); o[1] = f2bf(v[1]); o[2] = f2bf(v[2]); o[3] = f2bf(v[3]);
    *(ushort4v*)(ebf + (size_t)r * NE + lane * 4) = o;
}

// ---------------- input projection GEMM: Xp[d][t][g][s] = e @ Wih^T + bih + bhh ----------------
__launch_bounds__(256)
__global__ void k_xproj(const unsigned short* ebf, const unsigned short* Wb_ih,
                        const float* bih_f, const float* bhh_f,
                        const float* bih_b, const float* bhh_b,
                        unsigned short* Xp)
{
    int dir = blockIdx.z;
    int r0 = blockIdx.x * 64;
    int t = r0 / NS, s0 = r0 % NS;
    int g0 = blockIdx.y * 64;
    int tid = threadIdx.x;
    int w = tid >> 6, lane = tid & 63;
    int wr = w >> 1, wc = w & 1;
    int lrow = lane & 15, kg = lane >> 4;
    const float* bih = dir ? bih_b : bih_f;
    const float* bhh = dir ? bhh_b : bhh_f;

    const unsigned short* ap[2];
    const unsigned short* bp[2];
#pragma unroll
    for (int mi = 0; mi < 2; ++mi)
        ap[mi] = ebf + (size_t)(r0 + wr * 32 + mi * 16 + lrow) * NE + kg * 8;
#pragma unroll
    for (int ni = 0; ni < 2; ++ni)
        bp[ni] = Wb_ih + ((size_t)dir * NG + (g0 + wc * 32 + ni * 16 + lrow)) * NE + kg * 8;

    f32x4 acc[2][2] = {};
#pragma unroll
    for (int kk = 0; kk < 8; ++kk) {
        short8 a0 = *(const short8*)(ap[0] + kk * 32);
        short8 a1 = *(const short8*)(ap[1] + kk * 32);
        short8 b0 = *(const short8*)(bp[0] + kk * 32);
        short8 b1 = *(const short8*)(bp[1] + kk * 32);
        acc[0][0] = __builtin_amdgcn_mfma_f32_16x16x32_bf16(a0, b0, acc[0][0], 0, 0, 0);
        acc[0][1] = __builtin_amdgcn_mfma_f32_16x16x32_bf16(a0, b1, acc[0][1], 0, 0, 0);
        acc[1][0] = __builtin_amdgcn_mfma_f32_16x16x32_bf16(a1, b0, acc[1][0], 0, 0, 0);
        acc[1][1] = __builtin_amdgcn_mfma_f32_16x16x32_bf16(a1, b1, acc[1][1], 0, 0, 0);
    }
#pragma unroll
    for (int ni = 0; ni < 2; ++ni) {
        int g = g0 + wc * 32 + ni * 16 + lrow;
        float bias = bih[g] + bhh[g];
#pragma unroll
        for (int mi = 0; mi < 2; ++mi) {
            int srow = s0 + wr * 32 + mi * 16 + kg * 4;
            unsigned short* dst = Xp + (((size_t)dir * NB + t) * NG + g) * NS + srow;
            unsigned o0 = f2bf(acc[mi][ni][0] + bias);
            unsigned o1 = f2bf(acc[mi][ni][1] + bias);
            unsigned o2 = f2bf(acc[mi][ni][2] + bias);
            unsigned o3 = f2bf(acc[mi][ni][3] + bias);
            uint2 pk; pk.x = o0 | (o1 << 16); pk.y = o2 | (o3 << 16);
            *(uint2*)dst = pk;
        }
    }
}

// ---------------- LSTM recurrence (32 steps) + fused FC into feats ----------------
__launch_bounds__(512, 2)
__global__ void k_lstm(const unsigned short* Wb_hh, const unsigned short* fcpad,
                       const unsigned short* Xp, const float* h0, const float* c0,
                       float* feats)
{
    __shared__ unsigned short h_lds[16 * 136];   // stride 136 bf16 (272B)
    __shared__ float gates_lds[16 * 516];        // stride 516 f32 (2064B)
    int dir = blockIdx.x >> 5;
    int s0 = (blockIdx.x & 31) * 16;
    int tid = threadIdx.x;
    int w = tid >> 6, lane = tid & 63;
    int lrow = lane & 15, kg = lane >> 4;
    int sl = tid >> 5, hq = tid & 31;

    // Whh fragments in registers: wave w owns gate cols [w*64, w*64+64)
    short8 bfr[4][4];
#pragma unroll
    for (int nf = 0; nf < 4; ++nf) {
        const unsigned short* p = Wb_hh + ((size_t)dir * NG + (w * 64 + nf * 16 + lrow)) * NH2 + kg * 8;
#pragma unroll
        for (int kf = 0; kf < 4; ++kf)
            bfr[nf][kf] = *(const short8*)(p + kf * 32);
    }
    short8 fcfr[4];
    if (w < 2) {
        const unsigned short* p = fcpad + ((size_t)dir * 32 + (w * 16 + lrow)) * NH2 + kg * 8;
#pragma unroll
        for (int kf = 0; kf < 4; ++kf)
            fcfr[kf] = *(const short8*)(p + kf * 32);
    }

    // stage h0, keep c in registers (4 elems per thread)
    float c[4];
    {
        f32x4 cv = *(const f32x4*)(c0 + ((size_t)dir * NS + s0 + sl) * NH2 + hq * 4);
        c[0] = cv[0]; c[1] = cv[1]; c[2] = cv[2]; c[3] = cv[3];
        f32x4 hv = *(const f32x4*)(h0 + ((size_t)dir * NS + s0 + sl) * NH2 + hq * 4);
        ushort4v hb; hb[0] = f2bf(hv[0]); hb[1] = f2bf(hv[1]); hb[2] = f2bf(hv[2]); hb[3] = f2bf(hv[3]);
        *(ushort4v*)&h_lds[sl * 136 + hq * 4] = hb;
    }
    __syncthreads();

    for (int t = 0; t < 32; ++t) {
        int tx = (dir == 0) ? t : 31 - t;
        // issue Xp loads early (consumed after MFMA)
        ushort4v xv[4];
#pragma unroll
        for (int nf = 0; nf < 4; ++nf) {
            int g = w * 64 + nf * 16 + lrow;
            xv[nf] = *(const ushort4v*)(Xp + (((size_t)dir * NB + tx) * NG + g) * NS + s0 + kg * 4);
        }
        short8 afr[4];
#pragma unroll
        for (int kf = 0; kf < 4; ++kf)
            afr[kf] = *(const short8*)&h_lds[lrow * 136 + kf * 32 + kg * 8];
        f32x4 acc[4] = {};
#pragma unroll
        for (int nf = 0; nf < 4; ++nf)
#pragma unroll
            for (int kf = 0; kf < 4; ++kf)
                acc[nf] = __builtin_amdgcn_mfma_f32_16x16x32_bf16(afr[kf], bfr[nf][kf], acc[nf], 0, 0, 0);

        // fused FC for h produced at previous step (h_lds still holds it)
        if (w < 2 && t > 0) {
            int bprev = (dir == 0) ? (t - 1) : (32 - t);
            f32x4 fa = {};
#pragma unroll
            for (int kf = 0; kf < 4; ++kf)
                fa = __builtin_amdgcn_mfma_f32_16x16x32_bf16(afr[kf], fcfr[kf], fa, 0, 0, 0);
            int col = w * 16 + lrow;
            if (col < NT) {
#pragma unroll
                for (int i = 0; i < 4; ++i)
                    atomicAdd(&feats[((size_t)bprev * NS + s0 + kg * 4 + i) * NT + col], fa[i]);
            }
        }
#pragma unroll
        for (int nf = 0; nf < 4; ++nf) {
            int g = w * 64 + nf * 16 + lrow;
#pragma unroll
            for (int i = 0; i < 4; ++i)
                gates_lds[(kg * 4 + i) * 516 + g] = acc[nf][i] + bf2f(xv[nf][i]);
        }
        __syncthreads();
        // gate mix + state update (4 h-elems per thread)
        {
            const float* gl = gates_lds + sl * 516 + hq * 4;
            f32x4 gi = *(const f32x4*)(gl);
            f32x4 gf = *(const f32x4*)(gl + 128);
            f32x4 gg = *(const f32x4*)(gl + 256);
            f32x4 go = *(const f32x4*)(gl + 384);
            ushort4v hb;
#pragma unroll
            for (int e = 0; e < 4; ++e) {
                float ci = sigmoidf_(gf[e]) * c[e] + sigmoidf_(gi[e]) * tanhf_(gg[e]);
                c[e] = ci;
                hb[e] = f2bf(sigmoidf_(go[e]) * tanhf_(ci));
            }
            *(ushort4v*)&h_lds[sl * 136 + hq * 4] = hb;
        }
        __syncthreads();
    }
    // FC for the last h
    if (w < 2) {
        int blast = (dir == 0) ? 31 : 0;
        short8 afr[4];
#pragma unroll
        for (int kf = 0; kf < 4; ++kf)
            afr[kf] = *(const short8*)&h_lds[lrow * 136 + kf * 32 + kg * 8];
        f32x4 fa = {};
#pragma unroll
        for (int kf = 0; kf < 4; ++kf)
            fa = __builtin_amdgcn_mfma_f32_16x16x32_bf16(afr[kf], fcfr[kf], fa, 0, 0, 0);
        int col = w * 16 + lrow;
        if (col < NT) {
#pragma unroll
            for (int i = 0; i < 4; ++i)
                atomicAdd(&feats[((size_t)blast * NS + s0 + kg * 4 + i) * NT + col], fa[i]);
        }
    }
}

// ---------------- CRF forward (scaled-exp domain) + gold score ----------------
__launch_bounds__(64)
__global__ void k_crf(const float* feats, const float* trans, const int* Y,
                      float* fwd_sc, float* gold_sc)
{
    __shared__ float fl[NS * NT];
    __shared__ float tl[NT * NT];
    __shared__ int yl[NS];
    int b = blockIdx.x;
    int lane = threadIdx.x;
    const float* fb = feats + (size_t)b * NS * NT;
    for (int i = lane; i < NS * NT / 4; i += 64)
        ((f32x4*)fl)[i] = ((const f32x4*)fb)[i];
    for (int i = lane; i < NT * NT; i += 64) tl[i] = trans[i];
    for (int i = lane; i < NS; i += 64) yl[i] = Y[b * NS + i];
    __syncthreads();

    bool act = lane < NT;
    int j = act ? lane : 0;
    float wrow[NT];
#pragma unroll
    for (int k = 0; k < NT; ++k) wrow[k] = __expf(tl[j * NT + k]);
    float wstop = __expf(tl[(NT - 1) * NT + j]);
    float s = (act && j == NT - 2) ? 1.f : 0.f;
    float logm = 0.f;
    float featv = fl[j];
    for (int t = 0; t < NS; ++t) {
        float featn = (t < NS - 1) ? fl[(t + 1) * NT + j] : 0.f;
        float ef = __expf(featv);
        float qa0 = 0.f, qa1 = 0.f, qa2 = 0.f, qa3 = 0.f;
#pragma unroll
        for (int k = 0; k < NT; ++k) {
            float sk = __shfl(s, k);
            if ((k & 3) == 0) qa0 += wrow[k] * sk;
            else if ((k & 3) == 1) qa1 += wrow[k] * sk;
            else if ((k & 3) == 2) qa2 += wrow[k] * sk;
            else qa3 += wrow[k] * sk;
        }
        float sp = act ? ((qa0 + qa1) + (qa2 + qa3)) * ef : 0.f;
        if (__any(sp >= 0x1p60f) || !__any(sp >= 0x1p-60f)) {
            float m = sp;
#pragma unroll
            for (int off = 32; off; off >>= 1)
                m = fmaxf(m, __shfl_xor(m, off));
            float rinv = __builtin_amdgcn_rcpf(m);
            sp = sp * rinv;
            logm += __logf(m);
        }
        s = sp;
        featv = featn;
    }
    float v = act ? s * wstop : 0.f;
#pragma unroll
    for (int off = 32; off; off >>= 1) v += __shfl_xor(v, off);
    float fwd = logm + __logf(v);

    // gold score
    float acc = 0.f;
    for (int ss = lane; ss < NS; ss += 64) {
        int y = yl[ss];
        int yp = ss ? yl[ss - 1] : (NT - 2);
        acc += fl[ss * NT + y] + tl[y * NT + yp];
    }
    if (lane == 0) acc += tl[(NT - 1) * NT + yl[NS - 1]];
#pragma unroll
    for (int off = 32; off; off >>= 1) acc += __shfl_xor(acc, off);
    if (lane == 0) { fwd_sc[b] = fwd; gold_sc[b] = acc; }
}

// ---------------- final: score + Y copy ----------------
__global__ void k_final(const float* fwd_sc, const float* gold_sc, const int* Y, float* out)
{
    int idx = blockIdx.x * blockDim.x + threadIdx.x;
    if (blockIdx.x == 0 && threadIdx.x < 64) {
        float v = (threadIdx.x < NB) ? (fwd_sc[threadIdx.x] - gold_sc[threadIdx.x]) : 0.f;
#pragma unroll
        for (int off = 32; off; off >>= 1) v += __shfl_xor(v, off);
        if (threadIdx.x == 0) out[0] = v * (1.f / NB);
    }
    if (idx < NB * NS) out[1 + idx] = (float)Y[idx];
}

extern "C" void kernel_launch(void* const* d_in, const int* in_sizes, int n_in,
                              void* d_out, int out_size, void* d_ws, size_t ws_size,
                              hipStream_t stream)
{
    const int* X = (const int*)d_in[0];
    const int* Y = (const int*)d_in[1];
    const float* emb = (const float*)d_in[2];
    const float* Wih_f = (const float*)d_in[3];
    const float* Whh_f = (const float*)d_in[4];
    const float* bih_f = (const float*)d_in[5];
    const float* bhh_f = (const float*)d_in[6];
    const float* Wih_b = (const float*)d_in[7];
    const float* Whh_b = (const float*)d_in[8];
    const float* bih_b = (const float*)d_in[9];
    const float* bhh_b = (const float*)d_in[10];
    const float* fcW = (const float*)d_in[11];
    const float* fcb = (const float*)d_in[12];
    const float* trans = (const float*)d_in[13];
    const float* h0 = (const float*)d_in[14];
    const float* c0 = (const float*)d_in[15];
    float* out = (float*)d_out;

    char* ws = (char*)d_ws;
    unsigned short* Wb_ih = (unsigned short*)(ws + 0);          // 524288 B
    unsigned short* Wb_hh = (unsigned short*)(ws + 524288);     // 262144 B
    unsigned short* fcpad = (unsigned short*)(ws + 786432);     // 16384 B
    unsigned short* Xp    = (unsigned short*)(ws + 802816);     // 33554432 B
    float* feats          = (float*)(ws + 34357248);            // 1441792 B
    float* fwd_sc         = (float*)(ws + 35799040);            // 128 B
    float* gold_sc        = (float*)(ws + 35799168);            // 128 B
    unsigned short* ebf   = (unsigned short*)(ws + 35799296);   // 8388608 B  (total ~42.2 MiB)

    k_prep<<<dim3(2976), dim3(256), 0, stream>>>(Wih_f, Wih_b, Whh_f, Whh_b, fcW, fcb,
                                                 Wb_ih, Wb_hh, fcpad, feats);
    k_embcvt<<<dim3(NB * NS), dim3(64), 0, stream>>>(X, emb, ebf);
    k_xproj<<<dim3(256, 8, 2), dim3(256), 0, stream>>>(ebf, Wb_ih, bih_f, bhh_f, bih_b, bhh_b, Xp);
    k_lstm<<<dim3(64), dim3(512), 0, stream>>>(Wb_hh, fcpad, Xp, h0, c0, feats);
    k_crf<<<dim3(NB), dim3(64), 0, stream>>>(feats, trans, Y, fwd_sc, gold_sc);
    k_final<<<dim3(64), dim3(256), 0, stream>>>(fwd_sc, gold_sc, Y, out);
    (void)in_sizes; (void)n_in; (void)out_size; (void)ws_size;
}

// Round 3
// 184.775 us; speedup vs baseline: 1.5773x; 1.5773x over previous
//
#include <hip/hip_runtime.h>
#include <hip/hip_bf16.h>
#include <stdint.h>

typedef __attribute__((ext_vector_type(8))) short short8;
typedef __attribute__((ext_vector_type(4))) float f32x4;
typedef __attribute__((ext_vector_type(4))) unsigned short ushort4v;

#define NB 32
#define NS 512
#define NE 256
#define NH2 128
#define NG 512
#define NT 22

__device__ __forceinline__ unsigned short f2bf(float f) {
    union { float f; unsigned u; } v; v.f = f;
    unsigned r = v.u + 0x7fffu + ((v.u >> 16) & 1u);
    return (unsigned short)(r >> 16);
}
__device__ __forceinline__ float bf2f(unsigned short b) {
    union { unsigned u; float f; } v; v.u = ((unsigned)b) << 16;
    return v.f;
}
__device__ __forceinline__ float sigmoidf_(float x) {
    return __builtin_amdgcn_rcpf(1.f + __expf(-x));
}
__device__ __forceinline__ float tanhf_(float x) {
    return 1.f - 2.f * __builtin_amdgcn_rcpf(__expf(2.f * x) + 1.f);
}

// ---------------- prep: weight conversions + feats init ----------------
__global__ void k_prep(const float* Wih_f, const float* Wih_b,
                       const float* Whh_f, const float* Whh_b,
                       const float* fcW, const float* fcb,
                       unsigned short* Wb_ih, unsigned short* Wb_hh,
                       unsigned short* fcpad, float* feats)
{
    int idx = blockIdx.x * blockDim.x + threadIdx.x;
    const int n1 = 2 * NG * NE;     // 262144
    const int n2 = 2 * NG * NH2;    // 131072
    const int n3 = 2 * 32 * NH2;    // 8192
    const int n4 = NB * NS * NT;    // 360448
    if (idx < n1) {
        const float* src = (idx < NG * NE) ? Wih_f : Wih_b;
        Wb_ih[idx] = f2bf(src[idx % (NG * NE)]);
    } else if (idx < n1 + n2) {
        int i2 = idx - n1;
        const float* src = (i2 < NG * NH2) ? Whh_f : Whh_b;
        Wb_hh[i2] = f2bf(src[i2 % (NG * NH2)]);
    } else if (idx < n1 + n2 + n3) {
        int i3 = idx - n1 - n2;
        int d = i3 / (32 * NH2);
        int j = (i3 / NH2) % 32;
        int k = i3 % NH2;
        fcpad[i3] = (j < NT) ? f2bf(fcW[j * 256 + d * NH2 + k]) : (unsigned short)0;
    } else if (idx < n1 + n2 + n3 + n4) {
        int i4 = idx - n1 - n2 - n3;
        feats[i4] = fcb[i4 % NT];
    }
}

// ---------------- embedding gather + bf16 convert ----------------
__global__ void k_embcvt(const int* X, const float* emb, unsigned short* ebf)
{
    int r = blockIdx.x;          // 16384 rows
    int lane = threadIdx.x;      // 64
    int xr = X[r];
    f32x4 v = *(const f32x4*)(emb + (size_t)xr * NE + lane * 4);
    ushort4v o;
    o[0] = f2bf(v[0]); o[1] = f2bf(v[1]); o[2] = f2bf(v[2]); o[3] = f2bf(v[3]);
    *(ushort4v*)(ebf + (size_t)r * NE + lane * 4) = o;
}

// ---------------- input projection GEMM ----------------
__launch_bounds__(256)
__global__ void k_xproj(const unsigned short* ebf, const unsigned short* Wb_ih,
                        const float* bih_f, const float* bhh_f,
                        const float* bih_b, const float* bhh_b,
                        unsigned short* Xp)
{
    int dir = blockIdx.z;
    int r0 = blockIdx.x * 64;
    int t = r0 / NS, s0 = r0 % NS;
    int g0 = blockIdx.y * 64;
    int tid = threadIdx.x;
    int w = tid >> 6, lane = tid & 63;
    int wr = w >> 1, wc = w & 1;
    int lrow = lane & 15, kg = lane >> 4;
    const float* bih = dir ? bih_b : bih_f;
    const float* bhh = dir ? bhh_b : bhh_f;

    const unsigned short* ap[2];
    const unsigned short* bp[2];
#pragma unroll
    for (int mi = 0; mi < 2; ++mi)
        ap[mi] = ebf + (size_t)(r0 + wr * 32 + mi * 16 + lrow) * NE + kg * 8;
#pragma unroll
    for (int ni = 0; ni < 2; ++ni)
        bp[ni] = Wb_ih + ((size_t)dir * NG + (g0 + wc * 32 + ni * 16 + lrow)) * NE + kg * 8;

    f32x4 acc[2][2] = {};
#pragma unroll
    for (int kk = 0; kk < 8; ++kk) {
        short8 a0 = *(const short8*)(ap[0] + kk * 32);
        short8 a1 = *(const short8*)(ap[1] + kk * 32);
        short8 b0 = *(const short8*)(bp[0] + kk * 32);
        short8 b1 = *(const short8*)(bp[1] + kk * 32);
        acc[0][0] = __builtin_amdgcn_mfma_f32_16x16x32_bf16(a0, b0, acc[0][0], 0, 0, 0);
        acc[0][1] = __builtin_amdgcn_mfma_f32_16x16x32_bf16(a0, b1, acc[0][1], 0, 0, 0);
        acc[1][0] = __builtin_amdgcn_mfma_f32_16x16x32_bf16(a1, b0, acc[1][0], 0, 0, 0);
        acc[1][1] = __builtin_amdgcn_mfma_f32_16x16x32_bf16(a1, b1, acc[1][1], 0, 0, 0);
    }
#pragma unroll
    for (int ni = 0; ni < 2; ++ni) {
        int g = g0 + wc * 32 + ni * 16 + lrow;
        float bias = bih[g] + bhh[g];
#pragma unroll
        for (int mi = 0; mi < 2; ++mi) {
            int srow = s0 + wr * 32 + mi * 16 + kg * 4;
            unsigned short* dst = Xp + (((size_t)dir * NB + t) * NG + g) * NS + srow;
            unsigned o0 = f2bf(acc[mi][ni][0] + bias);
            unsigned o1 = f2bf(acc[mi][ni][1] + bias);
            unsigned o2 = f2bf(acc[mi][ni][2] + bias);
            unsigned o3 = f2bf(acc[mi][ni][3] + bias);
            uint2 pk; pk.x = o0 | (o1 << 16); pk.y = o2 | (o3 << 16);
            *(uint2*)dst = pk;
        }
    }
}

// ---------------- LSTM recurrence (32 steps) + fused FC into feats ----------------
__launch_bounds__(512, 2)
__global__ void k_lstm(const unsigned short* Wb_hh, const unsigned short* fcpad,
                       const unsigned short* Xp, const float* h0, const float* c0,
                       float* feats)
{
    __shared__ unsigned short h_lds[16 * 136];
    __shared__ float gates_lds[16 * 516];
    int dir = blockIdx.x >> 5;
    int s0 = (blockIdx.x & 31) * 16;
    int tid = threadIdx.x;
    int w = tid >> 6, lane = tid & 63;
    int lrow = lane & 15, kg = lane >> 4;
    int sl = tid >> 5, hq = tid & 31;

    short8 bfr[4][4];
#pragma unroll
    for (int nf = 0; nf < 4; ++nf) {
        const unsigned short* p = Wb_hh + ((size_t)dir * NG + (w * 64 + nf * 16 + lrow)) * NH2 + kg * 8;
#pragma unroll
        for (int kf = 0; kf < 4; ++kf)
            bfr[nf][kf] = *(const short8*)(p + kf * 32);
    }
    short8 fcfr[4];
    if (w < 2) {
        const unsigned short* p = fcpad + ((size_t)dir * 32 + (w * 16 + lrow)) * NH2 + kg * 8;
#pragma unroll
        for (int kf = 0; kf < 4; ++kf)
            fcfr[kf] = *(const short8*)(p + kf * 32);
    }

    float c[4];
    {
        f32x4 cv = *(const f32x4*)(c0 + ((size_t)dir * NS + s0 + sl) * NH2 + hq * 4);
        c[0] = cv[0]; c[1] = cv[1]; c[2] = cv[2]; c[3] = cv[3];
        f32x4 hv = *(const f32x4*)(h0 + ((size_t)dir * NS + s0 + sl) * NH2 + hq * 4);
        ushort4v hb; hb[0] = f2bf(hv[0]); hb[1] = f2bf(hv[1]); hb[2] = f2bf(hv[2]); hb[3] = f2bf(hv[3]);
        *(ushort4v*)&h_lds[sl * 136 + hq * 4] = hb;
    }
    __syncthreads();

    for (int t = 0; t < 32; ++t) {
        int tx = (dir == 0) ? t : 31 - t;
        ushort4v xv[4];
#pragma unroll
        for (int nf = 0; nf < 4; ++nf) {
            int g = w * 64 + nf * 16 + lrow;
            xv[nf] = *(const ushort4v*)(Xp + (((size_t)dir * NB + tx) * NG + g) * NS + s0 + kg * 4);
        }
        short8 afr[4];
#pragma unroll
        for (int kf = 0; kf < 4; ++kf)
            afr[kf] = *(const short8*)&h_lds[lrow * 136 + kf * 32 + kg * 8];
        f32x4 acc[4] = {};
#pragma unroll
        for (int nf = 0; nf < 4; ++nf)
#pragma unroll
            for (int kf = 0; kf < 4; ++kf)
                acc[nf] = __builtin_amdgcn_mfma_f32_16x16x32_bf16(afr[kf], bfr[nf][kf], acc[nf], 0, 0, 0);

        if (w < 2 && t > 0) {
            int bprev = (dir == 0) ? (t - 1) : (32 - t);
            f32x4 fa = {};
#pragma unroll
            for (int kf = 0; kf < 4; ++kf)
                fa = __builtin_amdgcn_mfma_f32_16x16x32_bf16(afr[kf], fcfr[kf], fa, 0, 0, 0);
            int col = w * 16 + lrow;
            if (col < NT) {
#pragma unroll
                for (int i = 0; i < 4; ++i)
                    atomicAdd(&feats[((size_t)bprev * NS + s0 + kg * 4 + i) * NT + col], fa[i]);
            }
        }
#pragma unroll
        for (int nf = 0; nf < 4; ++nf) {
            int g = w * 64 + nf * 16 + lrow;
#pragma unroll
            for (int i = 0; i < 4; ++i)
                gates_lds[(kg * 4 + i) * 516 + g] = acc[nf][i] + bf2f(xv[nf][i]);
        }
        __syncthreads();
        {
            const float* gl = gates_lds + sl * 516 + hq * 4;
            f32x4 gi = *(const f32x4*)(gl);
            f32x4 gf = *(const f32x4*)(gl + 128);
            f32x4 gg = *(const f32x4*)(gl + 256);
            f32x4 go = *(const f32x4*)(gl + 384);
            ushort4v hb;
#pragma unroll
            for (int e = 0; e < 4; ++e) {
                float ci = sigmoidf_(gf[e]) * c[e] + sigmoidf_(gi[e]) * tanhf_(gg[e]);
                c[e] = ci;
                hb[e] = f2bf(sigmoidf_(go[e]) * tanhf_(ci));
            }
            *(ushort4v*)&h_lds[sl * 136 + hq * 4] = hb;
        }
        __syncthreads();
    }
    if (w < 2) {
        int blast = (dir == 0) ? 31 : 0;
        short8 afr[4];
#pragma unroll
        for (int kf = 0; kf < 4; ++kf)
            afr[kf] = *(const short8*)&h_lds[lrow * 136 + kf * 32 + kg * 8];
        f32x4 fa = {};
#pragma unroll
        for (int kf = 0; kf < 4; ++kf)
            fa = __builtin_amdgcn_mfma_f32_16x16x32_bf16(afr[kf], fcfr[kf], fa, 0, 0, 0);
        int col = w * 16 + lrow;
        if (col < NT) {
#pragma unroll
            for (int i = 0; i < 4; ++i)
                atomicAdd(&feats[((size_t)blast * NS + s0 + kg * 4 + i) * NT + col], fa[i]);
        }
    }
}

// ---------------- CRF: MFMA tree-reduction of transfer matrices ----------------
// Each 22x22 step matrix A_t[next,prev] = exp(trans[next,prev]) * exp(feat_t[next]),
// padded to 32x32 (zeros). Tree-combine C = B_later * A_earlier via 4x
// mfma_f32_16x16x32_bf16 per product, normalizing by max entry each level
// (log-scales accumulated). Matrices stored in ONE layout each, chosen by the
// parity of their consumer role: A-operand (even) -> transposed (T), B-operand
// (odd) -> row-major (R).

// computes C = R-matrix * T-matrix (one wave), returns max entry over all lanes
__device__ __forceinline__ float mm_combine(const unsigned short* Rb, const unsigned short* Tb,
                                            int lane, f32x4 c[2][2])
{
    int lrow = lane & 15, kg = lane >> 4;
    short8 a0 = *(const short8*)(Rb + lrow * 32 + kg * 8);
    short8 a1 = *(const short8*)(Rb + (16 + lrow) * 32 + kg * 8);
    short8 b0 = *(const short8*)(Tb + lrow * 32 + kg * 8);
    short8 b1 = *(const short8*)(Tb + (16 + lrow) * 32 + kg * 8);
    c[0][0] = __builtin_amdgcn_mfma_f32_16x16x32_bf16(a0, b0, c[0][0], 0, 0, 0);
    c[0][1] = __builtin_amdgcn_mfma_f32_16x16x32_bf16(a0, b1, c[0][1], 0, 0, 0);
    c[1][0] = __builtin_amdgcn_mfma_f32_16x16x32_bf16(a1, b0, c[1][0], 0, 0, 0);
    c[1][1] = __builtin_amdgcn_mfma_f32_16x16x32_bf16(a1, b1, c[1][1], 0, 0, 0);
    float mx = 0.f;
#pragma unroll
    for (int ti = 0; ti < 2; ++ti)
#pragma unroll
        for (int tj = 0; tj < 2; ++tj)
#pragma unroll
            for (int i = 0; i < 4; ++i) mx = fmaxf(mx, c[ti][tj][i]);
#pragma unroll
    for (int off = 32; off; off >>= 1) mx = fmaxf(mx, __shfl_xor(mx, off));
    return fmaxf(mx, 1e-30f);   // guard: rcp(denormal) would be inf
}

__device__ __forceinline__ void write_scaled(unsigned short* outp, bool Rlayout,
                                             int lane, const f32x4 c[2][2], float inv)
{
    int lrow = lane & 15, kg = lane >> 4;
    if (Rlayout) {
#pragma unroll
        for (int ti = 0; ti < 2; ++ti)
#pragma unroll
            for (int tj = 0; tj < 2; ++tj) {
                int cc = tj * 16 + lrow;
#pragma unroll
                for (int i = 0; i < 4; ++i) {
                    int r = ti * 16 + kg * 4 + i;
                    float v = (r < NT && cc < NT) ? c[ti][tj][i] * inv : 0.f;
                    outp[r * 32 + cc] = f2bf(v);
                }
            }
    } else {
#pragma unroll
        for (int ti = 0; ti < 2; ++ti)
#pragma unroll
            for (int tj = 0; tj < 2; ++tj) {
                int cc = tj * 16 + lrow;
                int r0 = ti * 16 + kg * 4;
                ushort4v pk;
#pragma unroll
                for (int i = 0; i < 4; ++i) {
                    int r = r0 + i;
                    float v = (r < NT && cc < NT) ? c[ti][tj][i] * inv : 0.f;
                    pk[i] = f2bf(v);
                }
                *(ushort4v*)(outp + cc * 32 + r0) = pk;
            }
    }
}

// stage 1: one block per (segment of 16 steps, batch chain); 16 leaves -> 1 matrix
__launch_bounds__(256)
__global__ void k_crf1(const float* feats, const float* trans,
                       unsigned short* Mseg, float* lscseg)
{
    __shared__ unsigned short mats[16 * 1024];   // 32 KB, 16 slots of 32x32 bf16
    __shared__ float etR[484], etT[484];
    __shared__ float ef[16 * 24];
    __shared__ float lscm[16];
    int seg = blockIdx.x, b = blockIdx.y;
    int tid = threadIdx.x;
    int w = tid >> 6, lane = tid & 63;

    for (int i = tid; i < 484; i += 256) {
        float e = __expf(trans[i]);
        etR[i] = e;
        etT[(i % NT) * NT + (i / NT)] = e;
    }
    for (int i = tid; i < 16 * NT; i += 256) {   // FIX: strided loop (352 > 256 threads)
        int t = i / NT, j = i % NT;
        ef[t * 24 + j] = __expf(feats[((size_t)b * NS + seg * 16 + t) * NT + j]);
    }
    if (tid < 16) lscm[tid] = 0.f;
    __syncthreads();

    // build leaves: t odd -> R layout [j][k]; t even -> T layout [k][j]
    for (int idx = tid; idx < 16 * 1024; idx += 256) {
        int t = idx >> 10, cell = idx & 1023, row = cell >> 5, col = cell & 31;
        float v = 0.f;
        if (row < NT && col < NT) {
            v = (t & 1) ? etR[row * NT + col] * ef[t * 24 + row]
                        : etT[row * NT + col] * ef[t * 24 + col];
        }
        mats[idx] = f2bf(v);
    }
    __syncthreads();

    for (int lvl = 0; lvl < 4; ++lvl) {
        int nP = 8 >> lvl;
        for (int p = w; p < nP; p += 4) {
            int aslot = (2 * p) << lvl, bslot = (2 * p + 1) << lvl;
            f32x4 c[2][2] = {};
            float mx = mm_combine(mats + bslot * 1024, mats + aslot * 1024, lane, c);
            float inv = __builtin_amdgcn_rcpf(mx);
            float nlsc = lscm[aslot] + lscm[bslot] + __logf(mx);
            if (lvl < 3) {
                write_scaled(mats + aslot * 1024, (p & 1) != 0, lane, c, inv);
                if (lane == 0) lscm[aslot] = nlsc;
            } else {
                write_scaled(Mseg + ((size_t)b * 32 + seg) * 1024, (seg & 1) != 0, lane, c, inv);
                if (lane == 0) lscseg[b * 32 + seg] = nlsc;
            }
        }
        __syncthreads();
    }
}

// stage 2: one block per batch chain; 32 segment matrices -> score; + gold score
__launch_bounds__(256)
__global__ void k_crf2(const unsigned short* Mseg, const float* lscseg,
                       const float* feats, const float* trans, const int* Y,
                       float* fwd_sc, float* gold_sc)
{
    __shared__ unsigned short mats[16 * 1024];   // 32 KB
    __shared__ float lscm[16];
    __shared__ float tl[484];
    __shared__ float col20[32];
    __shared__ float red[4];
    int b = blockIdx.x;
    int tid = threadIdx.x;
    int w = tid >> 6, lane = tid & 63;
    int lrow = lane & 15, kg = lane >> 4;

    for (int i = tid; i < 484; i += 256) tl[i] = trans[i];
    __syncthreads();

    // level 0: operands straight from global (L2-hot), 16 products
    const unsigned short* base = Mseg + (size_t)b * 32 * 1024;
    for (int p = w; p < 16; p += 4) {
        f32x4 c[2][2] = {};
        float mx = mm_combine(base + (2 * p + 1) * 1024, base + (2 * p) * 1024, lane, c);
        float inv = __builtin_amdgcn_rcpf(mx);
        float nlsc = lscseg[b * 32 + 2 * p] + lscseg[b * 32 + 2 * p + 1] + __logf(mx);
        write_scaled(mats + p * 1024, (p & 1) != 0, lane, c, inv);
        if (lane == 0) lscm[p] = nlsc;
    }
    __syncthreads();

    for (int lvl = 0; lvl < 4; ++lvl) {
        int nP = 8 >> lvl;
        for (int p = w; p < nP; p += 4) {
            int aslot = (2 * p) << lvl, bslot = (2 * p + 1) << lvl;
            f32x4 c[2][2] = {};
            float mx = mm_combine(mats + bslot * 1024, mats + aslot * 1024, lane, c);
            if (lvl < 3) {
                float inv = __builtin_amdgcn_rcpf(mx);
                float nlsc = lscm[aslot] + lscm[bslot] + __logf(mx);
                write_scaled(mats + aslot * 1024, (p & 1) != 0, lane, c, inv);
                if (lane == 0) lscm[aslot] = nlsc;
            } else {
                // root: no normalization; extract column 20 (start tag)
                if (lrow == 4) {
#pragma unroll
                    for (int ti = 0; ti < 2; ++ti)
#pragma unroll
                        for (int i = 0; i < 4; ++i)
                            col20[ti * 16 + kg * 4 + i] = c[ti][1][i];
                }
                if (lane == 0) lscm[0] = lscm[0] + lscm[8];
            }
        }
        __syncthreads();
    }

    if (w == 0) {
        float v = 0.f;
        if (lane < NT) v = __expf(tl[(NT - 1) * NT + lane]) * col20[lane];
#pragma unroll
        for (int off = 32; off; off >>= 1) v += __shfl_xor(v, off);
        if (lane == 0) fwd_sc[b] = __logf(v) + lscm[0];
    }

    // gold score
    const float* fb = feats + (size_t)b * NS * NT;
    float acc = 0.f;
    for (int s = tid; s < NS; s += 256) {
        int y = Y[b * NS + s];
        int yp = s ? Y[b * NS + s - 1] : (NT - 2);
        acc += fb[s * NT + y] + tl[y * NT + yp];
    }
    if (tid == 0) acc += tl[(NT - 1) * NT + Y[b * NS + NS - 1]];
#pragma unroll
    for (int off = 32; off; off >>= 1) acc += __shfl_xor(acc, off);
    if (lane == 0) red[w] = acc;
    __syncthreads();
    if (tid == 0) gold_sc[b] = red[0] + red[1] + red[2] + red[3];
}

// ---------------- final: score + Y copy ----------------
__global__ void k_final(const float* fwd_sc, const float* gold_sc, const int* Y, float* out)
{
    int idx = blockIdx.x * blockDim.x + threadIdx.x;
    if (blockIdx.x == 0 && threadIdx.x < 64) {
        float v = (threadIdx.x < NB) ? (fwd_sc[threadIdx.x] - gold_sc[threadIdx.x]) : 0.f;
#pragma unroll
        for (int off = 32; off; off >>= 1) v += __shfl_xor(v, off);
        if (threadIdx.x == 0) out[0] = v * (1.f / NB);
    }
    if (idx < NB * NS) out[1 + idx] = (float)Y[idx];
}

extern "C" void kernel_launch(void* const* d_in, const int* in_sizes, int n_in,
                              void* d_out, int out_size, void* d_ws, size_t ws_size,
                              hipStream_t stream)
{
    const int* X = (const int*)d_in[0];
    const int* Y = (const int*)d_in[1];
    const float* emb = (const float*)d_in[2];
    const float* Wih_f = (const float*)d_in[3];
    const float* Whh_f = (const float*)d_in[4];
    const float* bih_f = (const float*)d_in[5];
    const float* bhh_f = (const float*)d_in[6];
    const float* Wih_b = (const float*)d_in[7];
    const float* Whh_b = (const float*)d_in[8];
    const float* bih_b = (const float*)d_in[9];
    const float* bhh_b = (const float*)d_in[10];
    const float* fcW = (const float*)d_in[11];
    const float* fcb = (const float*)d_in[12];
    const float* trans = (const float*)d_in[13];
    const float* h0 = (const float*)d_in[14];
    const float* c0 = (const float*)d_in[15];
    float* out = (float*)d_out;

    char* ws = (char*)d_ws;
    unsigned short* Wb_ih = (unsigned short*)(ws + 0);          // 524288 B
    unsigned short* Wb_hh = (unsigned short*)(ws + 524288);     // 262144 B
    unsigned short* fcpad = (unsigned short*)(ws + 786432);     // 16384 B
    unsigned short* Xp    = (unsigned short*)(ws + 802816);     // 33554432 B
    float* feats          = (float*)(ws + 34357248);            // 1441792 B
    float* fwd_sc         = (float*)(ws + 35799040);            // 128 B
    float* gold_sc        = (float*)(ws + 35799168);            // 128 B
    unsigned short* ebf   = (unsigned short*)(ws + 35799296);   // 8388608 B
    // Mseg/lscseg reuse the ebf region (ebf dead after k_xproj)
    unsigned short* Mseg  = ebf;                                // 2097152 B
    float* lscseg         = (float*)(ws + 35799296 + 2097152);  // 4096 B

    k_prep<<<dim3(2976), dim3(256), 0, stream>>>(Wih_f, Wih_b, Whh_f, Whh_b, fcW, fcb,
                                                 Wb_ih, Wb_hh, fcpad, feats);
    k_embcvt<<<dim3(NB * NS), dim3(64), 0, stream>>>(X, emb, ebf);
    k_xproj<<<dim3(256, 8, 2), dim3(256), 0, stream>>>(ebf, Wb_ih, bih_f, bhh_f, bih_b, bhh_b, Xp);
    k_lstm<<<dim3(64), dim3(512), 0, stream>>>(Wb_hh, fcpad, Xp, h0, c0, feats);
    k_crf1<<<dim3(32, 32), dim3(256), 0, stream>>>(feats, trans, Mseg, lscseg);
    k_crf2<<<dim3(NB), dim3(256), 0, stream>>>(Mseg, lscseg, feats, trans, Y, fwd_sc, gold_sc);
    k_final<<<dim3(64), dim3(256), 0, stream>>>(fwd_sc, gold_sc, Y, out);
    (void)in_sizes; (void)n_in; (void)out_size; (void)ws_size;
}

// Round 4
// 154.134 us; speedup vs baseline: 1.8909x; 1.1988x over previous
//
#include <hip/hip_runtime.h>
#include <hip/hip_bf16.h>
#include <stdint.h>

typedef __attribute__((ext_vector_type(8))) short short8;
typedef __attribute__((ext_vector_type(4))) float f32x4;
typedef __attribute__((ext_vector_type(4))) unsigned short ushort4v;

#define NB 32
#define NS 512
#define NE 256
#define NH2 128
#define NG 512
#define NT 22

__device__ __forceinline__ unsigned short f2bf(float f) {
    union { float f; unsigned u; } v; v.f = f;
    unsigned r = v.u + 0x7fffu + ((v.u >> 16) & 1u);
    return (unsigned short)(r >> 16);
}
__device__ __forceinline__ float bf2f(unsigned short b) {
    union { unsigned u; float f; } v; v.u = ((unsigned)b) << 16;
    return v.f;
}
__device__ __forceinline__ float sigmoidf_(float x) {
    return __builtin_amdgcn_rcpf(1.f + __expf(-x));
}
__device__ __forceinline__ float tanhf_(float x) {
    return 1.f - 2.f * __builtin_amdgcn_rcpf(__expf(2.f * x) + 1.f);
}
// raw workgroup barrier: LDS-only ordering, leaves global loads/stores in flight
__device__ __forceinline__ void wg_barrier() {
    __builtin_amdgcn_sched_barrier(0);
    asm volatile("s_waitcnt lgkmcnt(0)" ::: "memory");
    __builtin_amdgcn_s_barrier();
    __builtin_amdgcn_sched_barrier(0);
}

// ---------------- prep: weight conversions ----------------
__global__ void k_prep(const float* Wih_f, const float* Wih_b,
                       const float* Whh_f, const float* Whh_b,
                       const float* fcW,
                       unsigned short* Wb_ih, unsigned short* Wb_hh,
                       unsigned short* fcpad)
{
    int idx = blockIdx.x * blockDim.x + threadIdx.x;
    const int n1 = 2 * NG * NE;     // 262144
    const int n2 = 2 * NG * NH2;    // 131072
    const int n3 = 2 * 32 * NH2;    // 8192
    if (idx < n1) {
        const float* src = (idx < NG * NE) ? Wih_f : Wih_b;
        Wb_ih[idx] = f2bf(src[idx % (NG * NE)]);
    } else if (idx < n1 + n2) {
        int i2 = idx - n1;
        const float* src = (i2 < NG * NH2) ? Whh_f : Whh_b;
        Wb_hh[i2] = f2bf(src[i2 % (NG * NH2)]);
    } else if (idx < n1 + n2 + n3) {
        int i3 = idx - n1 - n2;
        int d = i3 / (32 * NH2);
        int j = (i3 / NH2) % 32;
        int k = i3 % NH2;
        fcpad[i3] = (j < NT) ? f2bf(fcW[j * 256 + d * NH2 + k]) : (unsigned short)0;
    }
}

// ---------------- embedding gather + bf16 convert ----------------
__global__ void k_embcvt(const int* X, const float* emb, unsigned short* ebf)
{
    int r = blockIdx.x;          // 16384 rows
    int lane = threadIdx.x;      // 64
    int xr = X[r];
    f32x4 v = *(const f32x4*)(emb + (size_t)xr * NE + lane * 4);
    ushort4v o;
    o[0] = f2bf(v[0]); o[1] = f2bf(v[1]); o[2] = f2bf(v[2]); o[3] = f2bf(v[3]);
    *(ushort4v*)(ebf + (size_t)r * NE + lane * 4) = o;
}

// ---------------- input projection GEMM -> block-local Xp layout ----------------
// Xp[dir][sb(32)][t(32)][g(512)][16 s]  (slot = 8192 bf16 = 16KB)
__launch_bounds__(256)
__global__ void k_xproj(const unsigned short* ebf, const unsigned short* Wb_ih,
                        const float* bih_f, const float* bhh_f,
                        const float* bih_b, const float* bhh_b,
                        unsigned short* Xp)
{
    int dir = blockIdx.z;
    int r0 = blockIdx.x * 64;
    int t = r0 / NS, s0 = r0 % NS;
    int g0 = blockIdx.y * 64;
    int tid = threadIdx.x;
    int w = tid >> 6, lane = tid & 63;
    int wr = w >> 1, wc = w & 1;
    int lrow = lane & 15, kg = lane >> 4;
    const float* bih = dir ? bih_b : bih_f;
    const float* bhh = dir ? bhh_b : bhh_f;

    const unsigned short* ap[2];
    const unsigned short* bp[2];
#pragma unroll
    for (int mi = 0; mi < 2; ++mi)
        ap[mi] = ebf + (size_t)(r0 + wr * 32 + mi * 16 + lrow) * NE + kg * 8;
#pragma unroll
    for (int ni = 0; ni < 2; ++ni)
        bp[ni] = Wb_ih + ((size_t)dir * NG + (g0 + wc * 32 + ni * 16 + lrow)) * NE + kg * 8;

    f32x4 acc[2][2] = {};
#pragma unroll
    for (int kk = 0; kk < 8; ++kk) {
        short8 a0 = *(const short8*)(ap[0] + kk * 32);
        short8 a1 = *(const short8*)(ap[1] + kk * 32);
        short8 b0 = *(const short8*)(bp[0] + kk * 32);
        short8 b1 = *(const short8*)(bp[1] + kk * 32);
        acc[0][0] = __builtin_amdgcn_mfma_f32_16x16x32_bf16(a0, b0, acc[0][0], 0, 0, 0);
        acc[0][1] = __builtin_amdgcn_mfma_f32_16x16x32_bf16(a0, b1, acc[0][1], 0, 0, 0);
        acc[1][0] = __builtin_amdgcn_mfma_f32_16x16x32_bf16(a1, b0, acc[1][0], 0, 0, 0);
        acc[1][1] = __builtin_amdgcn_mfma_f32_16x16x32_bf16(a1, b1, acc[1][1], 0, 0, 0);
    }
#pragma unroll
    for (int ni = 0; ni < 2; ++ni) {
        int g = g0 + wc * 32 + ni * 16 + lrow;
        float bias = bih[g] + bhh[g];
#pragma unroll
        for (int mi = 0; mi < 2; ++mi) {
            int srow = s0 + wr * 32 + mi * 16 + kg * 4;
            int sb = srow >> 4;
            unsigned short* dst = Xp + ((((size_t)dir * 32 + sb) * 32 + t) << 13) + g * 16 + (srow & 15);
            unsigned o0 = f2bf(acc[mi][ni][0] + bias);
            unsigned o1 = f2bf(acc[mi][ni][1] + bias);
            unsigned o2 = f2bf(acc[mi][ni][2] + bias);
            unsigned o3 = f2bf(acc[mi][ni][3] + bias);
            uint2 pk; pk.x = o0 | (o1 << 16); pk.y = o2 | (o3 << 16);
            *(uint2*)dst = pk;
        }
    }
}

// ---------------- LSTM recurrence (32 steps), barrier-light, prefetched ----------------
// h(t) is stored (bf16) into the just-consumed Xp slot (dir,sb,tx):
//   Hout(dir,sb,tx) = Xp + slot*8192, chunk [16 s][128 d].
__launch_bounds__(512, 2)
__global__ void k_lstm(const unsigned short* Wb_hh, unsigned short* Xp,
                       const float* h0, const float* c0)
{
    __shared__ unsigned short h_lds[16 * 136];
    __shared__ float gates_lds[16 * 516];
    int dir = blockIdx.x >> 5;
    int sb = blockIdx.x & 31;
    int s0 = sb * 16;
    int tid = threadIdx.x;
    int w = tid >> 6, lane = tid & 63;
    int lrow = lane & 15, kg = lane >> 4;
    int sl = tid >> 5, hq = tid & 31;

    short8 bfr[4][4];
#pragma unroll
    for (int nf = 0; nf < 4; ++nf) {
        const unsigned short* p = Wb_hh + ((size_t)dir * NG + (w * 64 + nf * 16 + lrow)) * NH2 + kg * 8;
#pragma unroll
        for (int kf = 0; kf < 4; ++kf)
            bfr[nf][kf] = *(const short8*)(p + kf * 32);
    }

    float c[4];
    {
        f32x4 cv = *(const f32x4*)(c0 + ((size_t)dir * NS + s0 + sl) * NH2 + hq * 4);
        c[0] = cv[0]; c[1] = cv[1]; c[2] = cv[2]; c[3] = cv[3];
        f32x4 hv = *(const f32x4*)(h0 + ((size_t)dir * NS + s0 + sl) * NH2 + hq * 4);
        ushort4v hb; hb[0] = f2bf(hv[0]); hb[1] = f2bf(hv[1]); hb[2] = f2bf(hv[2]); hb[3] = f2bf(hv[3]);
        *(ushort4v*)&h_lds[sl * 136 + hq * 4] = hb;
    }

    // prologue prefetch: Xp(tx0), per-wave contiguous 2KB chunk
    unsigned short* xslot0 = Xp + (((size_t)dir * 32 + sb) * 32) * 8192;
    const unsigned short* xlane = xslot0 + (w * 64 + lrow) * 16 + kg * 4;
    int tx0 = dir ? 31 : 0;
    ushort4v xv[4], xvn[4];
#pragma unroll
    for (int nf = 0; nf < 4; ++nf)
        xv[nf] = *(const ushort4v*)(xlane + (size_t)tx0 * 8192 + nf * 256);
    __syncthreads();   // prologue barrier (full drain OK, once)

    for (int t = 0; t < 32; ++t) {
        int tx  = dir ? 31 - t : t;
        int txn = dir ? 30 - t : t + 1;
        // issue next-step prefetch early (stays in flight across raw barriers)
        if (t < 31) {
#pragma unroll
            for (int nf = 0; nf < 4; ++nf)
                xvn[nf] = *(const ushort4v*)(xlane + (size_t)txn * 8192 + nf * 256);
        }
        short8 afr[4];
#pragma unroll
        for (int kf = 0; kf < 4; ++kf)
            afr[kf] = *(const short8*)&h_lds[lrow * 136 + kf * 32 + kg * 8];
        f32x4 acc[4] = {};
#pragma unroll
        for (int nf = 0; nf < 4; ++nf)
#pragma unroll
            for (int kf = 0; kf < 4; ++kf)
                acc[nf] = __builtin_amdgcn_mfma_f32_16x16x32_bf16(afr[kf], bfr[nf][kf], acc[nf], 0, 0, 0);
#pragma unroll
        for (int nf = 0; nf < 4; ++nf) {
            int g = w * 64 + nf * 16 + lrow;
#pragma unroll
            for (int i = 0; i < 4; ++i)
                gates_lds[(kg * 4 + i) * 516 + g] = acc[nf][i] + bf2f(xv[nf][i]);
        }
        wg_barrier();
        {
            const float* gl = gates_lds + sl * 516 + hq * 4;
            f32x4 gi = *(const f32x4*)(gl);
            f32x4 gf = *(const f32x4*)(gl + 128);
            f32x4 gg = *(const f32x4*)(gl + 256);
            f32x4 go = *(const f32x4*)(gl + 384);
            ushort4v hb;
#pragma unroll
            for (int e = 0; e < 4; ++e) {
                float ci = sigmoidf_(gf[e]) * c[e] + sigmoidf_(gi[e]) * tanhf_(gg[e]);
                c[e] = ci;
                hb[e] = f2bf(sigmoidf_(go[e]) * tanhf_(ci));
            }
            *(ushort4v*)&h_lds[sl * 136 + hq * 4] = hb;
            // store h(tx) into the consumed Xp slot (fire-and-forget)
            *(ushort4v*)(xslot0 + (size_t)tx * 8192 + sl * 128 + hq * 4) = hb;
        }
        wg_barrier();
#pragma unroll
        for (int nf = 0; nf < 4; ++nf) xv[nf] = xvn[nf];
    }
}

// ---------------- FC: feats[t][s][tag] = [hf|hb] @ fcW^T + fcb ----------------
__launch_bounds__(64)
__global__ void k_fc(const unsigned short* Hout, const unsigned short* fcpad,
                     const float* fcb, float* feats)
{
    int t = blockIdx.x, sb = blockIdx.y;
    int lane = threadIdx.x;
    int lrow = lane & 15, kg = lane >> 4;
    f32x4 acc[2] = {};
#pragma unroll
    for (int dir = 0; dir < 2; ++dir) {
        const unsigned short* hb = Hout + ((((size_t)dir * 32 + sb) * 32 + t) << 13) + lrow * 128 + kg * 8;
        const unsigned short* fb = fcpad + dir * 4096 + lrow * 128 + kg * 8;
#pragma unroll
        for (int kf = 0; kf < 4; ++kf) {
            short8 a  = *(const short8*)(hb + kf * 32);
            short8 b0 = *(const short8*)(fb + kf * 32);
            short8 b1 = *(const short8*)(fb + 2048 + kf * 32);
            acc[0] = __builtin_amdgcn_mfma_f32_16x16x32_bf16(a, b0, acc[0], 0, 0, 0);
            acc[1] = __builtin_amdgcn_mfma_f32_16x16x32_bf16(a, b1, acc[1], 0, 0, 0);
        }
    }
#pragma unroll
    for (int nf = 0; nf < 2; ++nf) {
        int tag = nf * 16 + lrow;
        if (tag < NT) {
            float bias = fcb[tag];
#pragma unroll
            for (int i = 0; i < 4; ++i)
                feats[((size_t)t * NS + sb * 16 + kg * 4 + i) * NT + tag] = acc[nf][i] + bias;
        }
    }
}

// ---------------- CRF: MFMA tree-reduction of transfer matrices ----------------
__device__ __forceinline__ float mm_combine(const unsigned short* Rb, const unsigned short* Tb,
                                            int lane, f32x4 c[2][2])
{
    int lrow = lane & 15, kg = lane >> 4;
    short8 a0 = *(const short8*)(Rb + lrow * 32 + kg * 8);
    short8 a1 = *(const short8*)(Rb + (16 + lrow) * 32 + kg * 8);
    short8 b0 = *(const short8*)(Tb + lrow * 32 + kg * 8);
    short8 b1 = *(const short8*)(Tb + (16 + lrow) * 32 + kg * 8);
    c[0][0] = __builtin_amdgcn_mfma_f32_16x16x32_bf16(a0, b0, c[0][0], 0, 0, 0);
    c[0][1] = __builtin_amdgcn_mfma_f32_16x16x32_bf16(a0, b1, c[0][1], 0, 0, 0);
    c[1][0] = __builtin_amdgcn_mfma_f32_16x16x32_bf16(a1, b0, c[1][0], 0, 0, 0);
    c[1][1] = __builtin_amdgcn_mfma_f32_16x16x32_bf16(a1, b1, c[1][1], 0, 0, 0);
    float mx = 0.f;
#pragma unroll
    for (int ti = 0; ti < 2; ++ti)
#pragma unroll
        for (int tj = 0; tj < 2; ++tj)
#pragma unroll
            for (int i = 0; i < 4; ++i) mx = fmaxf(mx, c[ti][tj][i]);
#pragma unroll
    for (int off = 32; off; off >>= 1) mx = fmaxf(mx, __shfl_xor(mx, off));
    return fmaxf(mx, 1e-30f);
}

__device__ __forceinline__ void write_scaled(unsigned short* outp, bool Rlayout,
                                             int lane, const f32x4 c[2][2], float inv)
{
    int lrow = lane & 15, kg = lane >> 4;
    if (Rlayout) {
#pragma unroll
        for (int ti = 0; ti < 2; ++ti)
#pragma unroll
            for (int tj = 0; tj < 2; ++tj) {
                int cc = tj * 16 + lrow;
#pragma unroll
                for (int i = 0; i < 4; ++i) {
                    int r = ti * 16 + kg * 4 + i;
                    float v = (r < NT && cc < NT) ? c[ti][tj][i] * inv : 0.f;
                    outp[r * 32 + cc] = f2bf(v);
                }
            }
    } else {
#pragma unroll
        for (int ti = 0; ti < 2; ++ti)
#pragma unroll
            for (int tj = 0; tj < 2; ++tj) {
                int cc = tj * 16 + lrow;
                int r0 = ti * 16 + kg * 4;
                ushort4v pk;
#pragma unroll
                for (int i = 0; i < 4; ++i) {
                    int r = r0 + i;
                    float v = (r < NT && cc < NT) ? c[ti][tj][i] * inv : 0.f;
                    pk[i] = f2bf(v);
                }
                *(ushort4v*)(outp + cc * 32 + r0) = pk;
            }
    }
}

__launch_bounds__(256)
__global__ void k_crf1(const float* feats, const float* trans,
                       unsigned short* Mseg, float* lscseg)
{
    __shared__ unsigned short mats[16 * 1024];
    __shared__ float etR[484], etT[484];
    __shared__ float ef[16 * 24];
    __shared__ float lscm[16];
    int seg = blockIdx.x, b = blockIdx.y;
    int tid = threadIdx.x;
    int w = tid >> 6, lane = tid & 63;

    for (int i = tid; i < 484; i += 256) {
        float e = __expf(trans[i]);
        etR[i] = e;
        etT[(i % NT) * NT + (i / NT)] = e;
    }
    for (int i = tid; i < 16 * NT; i += 256) {
        int t = i / NT, j = i % NT;
        ef[t * 24 + j] = __expf(feats[((size_t)b * NS + seg * 16 + t) * NT + j]);
    }
    if (tid < 16) lscm[tid] = 0.f;
    __syncthreads();

    for (int idx = tid; idx < 16 * 1024; idx += 256) {
        int t = idx >> 10, cell = idx & 1023, row = cell >> 5, col = cell & 31;
        float v = 0.f;
        if (row < NT && col < NT) {
            v = (t & 1) ? etR[row * NT + col] * ef[t * 24 + row]
                        : etT[row * NT + col] * ef[t * 24 + col];
        }
        mats[idx] = f2bf(v);
    }
    __syncthreads();

    for (int lvl = 0; lvl < 4; ++lvl) {
        int nP = 8 >> lvl;
        for (int p = w; p < nP; p += 4) {
            int aslot = (2 * p) << lvl, bslot = (2 * p + 1) << lvl;
            f32x4 c[2][2] = {};
            float mx = mm_combine(mats + bslot * 1024, mats + aslot * 1024, lane, c);
            float inv = __builtin_amdgcn_rcpf(mx);
            float nlsc = lscm[aslot] + lscm[bslot] + __logf(mx);
            if (lvl < 3) {
                write_scaled(mats + aslot * 1024, (p & 1) != 0, lane, c, inv);
                if (lane == 0) lscm[aslot] = nlsc;
            } else {
                write_scaled(Mseg + ((size_t)b * 32 + seg) * 1024, (seg & 1) != 0, lane, c, inv);
                if (lane == 0) lscseg[b * 32 + seg] = nlsc;
            }
        }
        __syncthreads();
    }
}

__launch_bounds__(256)
__global__ void k_crf2(const unsigned short* Mseg, const float* lscseg,
                       const float* feats, const float* trans, const int* Y,
                       float* fwd_sc, float* gold_sc)
{
    __shared__ unsigned short mats[16 * 1024];
    __shared__ float lscm[16];
    __shared__ float tl[484];
    __shared__ float col20[32];
    __shared__ float red[4];
    int b = blockIdx.x;
    int tid = threadIdx.x;
    int w = tid >> 6, lane = tid & 63;
    int lrow = lane & 15, kg = lane >> 4;

    for (int i = tid; i < 484; i += 256) tl[i] = trans[i];
    __syncthreads();

    const unsigned short* base = Mseg + (size_t)b * 32 * 1024;
    for (int p = w; p < 16; p += 4) {
        f32x4 c[2][2] = {};
        float mx = mm_combine(base + (2 * p + 1) * 1024, base + (2 * p) * 1024, lane, c);
        float inv = __builtin_amdgcn_rcpf(mx);
        float nlsc = lscseg[b * 32 + 2 * p] + lscseg[b * 32 + 2 * p + 1] + __logf(mx);
        write_scaled(mats + p * 1024, (p & 1) != 0, lane, c, inv);
        if (lane == 0) lscm[p] = nlsc;
    }
    __syncthreads();

    for (int lvl = 0; lvl < 4; ++lvl) {
        int nP = 8 >> lvl;
        for (int p = w; p < nP; p += 4) {
            int aslot = (2 * p) << lvl, bslot = (2 * p + 1) << lvl;
            f32x4 c[2][2] = {};
            float mx = mm_combine(mats + bslot * 1024, mats + aslot * 1024, lane, c);
            if (lvl < 3) {
                float inv = __builtin_amdgcn_rcpf(mx);
                float nlsc = lscm[aslot] + lscm[bslot] + __logf(mx);
                write_scaled(mats + aslot * 1024, (p & 1) != 0, lane, c, inv);
                if (lane == 0) lscm[aslot] = nlsc;
            } else {
                if (lrow == 4) {
#pragma unroll
                    for (int ti = 0; ti < 2; ++ti)
#pragma unroll
                        for (int i = 0; i < 4; ++i)
                            col20[ti * 16 + kg * 4 + i] = c[ti][1][i];
                }
                if (lane == 0) lscm[0] = lscm[0] + lscm[8];
            }
        }
        __syncthreads();
    }

    if (w == 0) {
        float v = 0.f;
        if (lane < NT) v = __expf(tl[(NT - 1) * NT + lane]) * col20[lane];
#pragma unroll
        for (int off = 32; off; off >>= 1) v += __shfl_xor(v, off);
        if (lane == 0) fwd_sc[b] = __logf(v) + lscm[0];
    }

    const float* fb = feats + (size_t)b * NS * NT;
    float acc = 0.f;
    for (int s = tid; s < NS; s += 256) {
        int y = Y[b * NS + s];
        int yp = s ? Y[b * NS + s - 1] : (NT - 2);
        acc += fb[s * NT + y] + tl[y * NT + yp];
    }
    if (tid == 0) acc += tl[(NT - 1) * NT + Y[b * NS + NS - 1]];
#pragma unroll
    for (int off = 32; off; off >>= 1) acc += __shfl_xor(acc, off);
    if (lane == 0) red[w] = acc;
    __syncthreads();
    if (tid == 0) gold_sc[b] = red[0] + red[1] + red[2] + red[3];
}

// ---------------- final: score + Y copy ----------------
__global__ void k_final(const float* fwd_sc, const float* gold_sc, const int* Y, float* out)
{
    int idx = blockIdx.x * blockDim.x + threadIdx.x;
    if (blockIdx.x == 0 && threadIdx.x < 64) {
        float v = (threadIdx.x < NB) ? (fwd_sc[threadIdx.x] - gold_sc[threadIdx.x]) : 0.f;
#pragma unroll
        for (int off = 32; off; off >>= 1) v += __shfl_xor(v, off);
        if (threadIdx.x == 0) out[0] = v * (1.f / NB);
    }
    if (idx < NB * NS) out[1 + idx] = (float)Y[idx];
}

extern "C" void kernel_launch(void* const* d_in, const int* in_sizes, int n_in,
                              void* d_out, int out_size, void* d_ws, size_t ws_size,
                              hipStream_t stream)
{
    const int* X = (const int*)d_in[0];
    const int* Y = (const int*)d_in[1];
    const float* emb = (const float*)d_in[2];
    const float* Wih_f = (const float*)d_in[3];
    const float* Whh_f = (const float*)d_in[4];
    const float* bih_f = (const float*)d_in[5];
    const float* bhh_f = (const float*)d_in[6];
    const float* Wih_b = (const float*)d_in[7];
    const float* Whh_b = (const float*)d_in[8];
    const float* bih_b = (const float*)d_in[9];
    const float* bhh_b = (const float*)d_in[10];
    const float* fcW = (const float*)d_in[11];
    const float* fcb = (const float*)d_in[12];
    const float* trans = (const float*)d_in[13];
    const float* h0 = (const float*)d_in[14];
    const float* c0 = (const float*)d_in[15];
    float* out = (float*)d_out;

    char* ws = (char*)d_ws;
    unsigned short* Wb_ih = (unsigned short*)(ws + 0);          // 524288 B
    unsigned short* Wb_hh = (unsigned short*)(ws + 524288);     // 262144 B
    unsigned short* fcpad = (unsigned short*)(ws + 786432);     // 16384 B
    unsigned short* Xp    = (unsigned short*)(ws + 802816);     // 33554432 B (doubles as Hout)
    float* feats          = (float*)(ws + 34357248);            // 1441792 B
    float* fwd_sc         = (float*)(ws + 35799040);            // 128 B
    float* gold_sc        = (float*)(ws + 35799168);            // 128 B
    unsigned short* ebf   = (unsigned short*)(ws + 35799296);   // 8388608 B
    unsigned short* Mseg  = ebf;                                // 2097152 B (ebf dead after k_xproj)
    float* lscseg         = (float*)(ws + 35799296 + 2097152);  // 4096 B

    k_prep<<<dim3(1568), dim3(256), 0, stream>>>(Wih_f, Wih_b, Whh_f, Whh_b, fcW,
                                                 Wb_ih, Wb_hh, fcpad);
    k_embcvt<<<dim3(NB * NS), dim3(64), 0, stream>>>(X, emb, ebf);
    k_xproj<<<dim3(256, 8, 2), dim3(256), 0, stream>>>(ebf, Wb_ih, bih_f, bhh_f, bih_b, bhh_b, Xp);
    k_lstm<<<dim3(64), dim3(512), 0, stream>>>(Wb_hh, Xp, h0, c0);
    k_fc<<<dim3(32, 32), dim3(64), 0, stream>>>(Xp, fcpad, fcb, feats);
    k_crf1<<<dim3(32, 32), dim3(256), 0, stream>>>(feats, trans, Mseg, lscseg);
    k_crf2<<<dim3(NB), dim3(256), 0, stream>>>(Mseg, lscseg, feats, trans, Y, fwd_sc, gold_sc);
    k_final<<<dim3(64), dim3(256), 0, stream>>>(fwd_sc, gold_sc, Y, out);
    (void)in_sizes; (void)n_in; (void)out_size; (void)ws_size;
}

// Round 5
// 152.811 us; speedup vs baseline: 1.9073x; 1.0087x over previous
//
#include <hip/hip_runtime.h>
#include <hip/hip_bf16.h>
#include <stdint.h>

typedef __attribute__((ext_vector_type(8))) short short8;
typedef __attribute__((ext_vector_type(4))) float f32x4;
typedef __attribute__((ext_vector_type(4))) unsigned short ushort4v;

#define NB 32
#define NS 512
#define NE 256
#define NH2 128
#define NG 512
#define NT 22

__device__ __forceinline__ unsigned short f2bf(float f) {
    union { float f; unsigned u; } v; v.f = f;
    unsigned r = v.u + 0x7fffu + ((v.u >> 16) & 1u);
    return (unsigned short)(r >> 16);
}
__device__ __forceinline__ float bf2f(unsigned short b) {
    union { unsigned u; float f; } v; v.u = ((unsigned)b) << 16;
    return v.f;
}
__device__ __forceinline__ float sigmoidf_(float x) {
    return __builtin_amdgcn_rcpf(1.f + __expf(-x));
}
__device__ __forceinline__ float tanhf_(float x) {
    return 1.f - 2.f * __builtin_amdgcn_rcpf(__expf(2.f * x) + 1.f);
}
// raw workgroup barrier: LDS-only ordering, leaves global loads/stores in flight
__device__ __forceinline__ void wg_barrier() {
    __builtin_amdgcn_sched_barrier(0);
    asm volatile("s_waitcnt lgkmcnt(0)" ::: "memory");
    __builtin_amdgcn_s_barrier();
    __builtin_amdgcn_sched_barrier(0);
}

// ---------------- prep: weight conversions ----------------
__global__ void k_prep(const float* Wih_f, const float* Wih_b,
                       const float* Whh_f, const float* Whh_b,
                       const float* fcW,
                       unsigned short* Wb_ih, unsigned short* Wb_hh,
                       unsigned short* fcpad)
{
    int idx = blockIdx.x * blockDim.x + threadIdx.x;
    const int n1 = 2 * NG * NE;     // 262144
    const int n2 = 2 * NG * NH2;    // 131072
    const int n3 = 2 * 32 * NH2;    // 8192
    if (idx < n1) {
        const float* src = (idx < NG * NE) ? Wih_f : Wih_b;
        Wb_ih[idx] = f2bf(src[idx % (NG * NE)]);
    } else if (idx < n1 + n2) {
        int i2 = idx - n1;
        const float* src = (i2 < NG * NH2) ? Whh_f : Whh_b;
        Wb_hh[i2] = f2bf(src[i2 % (NG * NH2)]);
    } else if (idx < n1 + n2 + n3) {
        int i3 = idx - n1 - n2;
        int d = i3 / (32 * NH2);
        int j = (i3 / NH2) % 32;
        int k = i3 % NH2;
        fcpad[i3] = (j < NT) ? f2bf(fcW[j * 256 + d * NH2 + k]) : (unsigned short)0;
    }
}

// ---------------- embedding gather + bf16 convert ----------------
__global__ void k_embcvt(const int* X, const float* emb, unsigned short* ebf)
{
    int r = blockIdx.x;          // 16384 rows
    int lane = threadIdx.x;      // 64
    int xr = X[r];
    f32x4 v = *(const f32x4*)(emb + (size_t)xr * NE + lane * 4);
    ushort4v o;
    o[0] = f2bf(v[0]); o[1] = f2bf(v[1]); o[2] = f2bf(v[2]); o[3] = f2bf(v[3]);
    *(ushort4v*)(ebf + (size_t)r * NE + lane * 4) = o;
}

// ---------------- input projection GEMM -> block-local Xp layout ----------------
// Xp[dir][sb(32)][t(32)][g(512)][16 s]  (slot = 8192 bf16 = 16KB)
// All 32 fragment loads issued up-front: 32-deep memory-level parallelism per
// wave (one base latency instead of 8 serial round-trips).
__launch_bounds__(256)
__global__ void k_xproj(const unsigned short* ebf, const unsigned short* Wb_ih,
                        const float* bih_f, const float* bhh_f,
                        const float* bih_b, const float* bhh_b,
                        unsigned short* Xp)
{
    int dir = blockIdx.z;
    int r0 = blockIdx.x * 64;
    int t = r0 / NS, s0 = r0 % NS;
    int g0 = blockIdx.y * 64;
    int tid = threadIdx.x;
    int w = tid >> 6, lane = tid & 63;
    int wr = w >> 1, wc = w & 1;
    int lrow = lane & 15, kg = lane >> 4;
    const float* bih = dir ? bih_b : bih_f;
    const float* bhh = dir ? bhh_b : bhh_f;

    const unsigned short* ap0 = ebf + (size_t)(r0 + wr * 32 + lrow) * NE + kg * 8;
    const unsigned short* ap1 = ap0 + 16 * NE;
    const unsigned short* bp0 = Wb_ih + ((size_t)dir * NG + (g0 + wc * 32 + lrow)) * NE + kg * 8;
    const unsigned short* bp1 = bp0 + 16 * NE;

    short8 av0[8], av1[8], bv0[8], bv1[8];
#pragma unroll
    for (int kk = 0; kk < 8; ++kk) {
        av0[kk] = *(const short8*)(ap0 + kk * 32);
        av1[kk] = *(const short8*)(ap1 + kk * 32);
        bv0[kk] = *(const short8*)(bp0 + kk * 32);
        bv1[kk] = *(const short8*)(bp1 + kk * 32);
    }

    f32x4 acc[2][2] = {};
#pragma unroll
    for (int kk = 0; kk < 8; ++kk) {
        acc[0][0] = __builtin_amdgcn_mfma_f32_16x16x32_bf16(av0[kk], bv0[kk], acc[0][0], 0, 0, 0);
        acc[0][1] = __builtin_amdgcn_mfma_f32_16x16x32_bf16(av0[kk], bv1[kk], acc[0][1], 0, 0, 0);
        acc[1][0] = __builtin_amdgcn_mfma_f32_16x16x32_bf16(av1[kk], bv0[kk], acc[1][0], 0, 0, 0);
        acc[1][1] = __builtin_amdgcn_mfma_f32_16x16x32_bf16(av1[kk], bv1[kk], acc[1][1], 0, 0, 0);
    }
#pragma unroll
    for (int ni = 0; ni < 2; ++ni) {
        int g = g0 + wc * 32 + ni * 16 + lrow;
        float bias = bih[g] + bhh[g];
#pragma unroll
        for (int mi = 0; mi < 2; ++mi) {
            int srow = s0 + wr * 32 + mi * 16 + kg * 4;
            int sb = srow >> 4;
            unsigned short* dst = Xp + ((((size_t)dir * 32 + sb) * 32 + t) << 13) + g * 16 + (srow & 15);
            unsigned o0 = f2bf(acc[mi][ni][0] + bias);
            unsigned o1 = f2bf(acc[mi][ni][1] + bias);
            unsigned o2 = f2bf(acc[mi][ni][2] + bias);
            unsigned o3 = f2bf(acc[mi][ni][3] + bias);
            uint2 pk; pk.x = o0 | (o1 << 16); pk.y = o2 | (o3 << 16);
            *(uint2*)dst = pk;
        }
    }
}

// ---------------- LSTM recurrence (32 steps), barrier-light, prefetched ----------------
// h(t) is stored (bf16) into the just-consumed Xp slot (dir,sb,tx):
//   Hout(dir,sb,tx) = Xp + slot*8192, chunk [16 s][128 d].
__launch_bounds__(512, 2)
__global__ void k_lstm(const unsigned short* Wb_hh, unsigned short* Xp,
                       const float* h0, const float* c0)
{
    __shared__ unsigned short h_lds[16 * 136];
    __shared__ float gates_lds[16 * 516];
    int dir = blockIdx.x >> 5;
    int sb = blockIdx.x & 31;
    int s0 = sb * 16;
    int tid = threadIdx.x;
    int w = tid >> 6, lane = tid & 63;
    int lrow = lane & 15, kg = lane >> 4;
    int sl = tid >> 5, hq = tid & 31;

    short8 bfr[4][4];
#pragma unroll
    for (int nf = 0; nf < 4; ++nf) {
        const unsigned short* p = Wb_hh + ((size_t)dir * NG + (w * 64 + nf * 16 + lrow)) * NH2 + kg * 8;
#pragma unroll
        for (int kf = 0; kf < 4; ++kf)
            bfr[nf][kf] = *(const short8*)(p + kf * 32);
    }

    float c[4];
    {
        f32x4 cv = *(const f32x4*)(c0 + ((size_t)dir * NS + s0 + sl) * NH2 + hq * 4);
        c[0] = cv[0]; c[1] = cv[1]; c[2] = cv[2]; c[3] = cv[3];
        f32x4 hv = *(const f32x4*)(h0 + ((size_t)dir * NS + s0 + sl) * NH2 + hq * 4);
        ushort4v hb; hb[0] = f2bf(hv[0]); hb[1] = f2bf(hv[1]); hb[2] = f2bf(hv[2]); hb[3] = f2bf(hv[3]);
        *(ushort4v*)&h_lds[sl * 136 + hq * 4] = hb;
    }

    // prologue prefetch: Xp(tx0), per-wave contiguous 2KB chunk
    unsigned short* xslot0 = Xp + (((size_t)dir * 32 + sb) * 32) * 8192;
    const unsigned short* xlane = xslot0 + (w * 64 + lrow) * 16 + kg * 4;
    int tx0 = dir ? 31 : 0;
    ushort4v xv[4], xvn[4];
#pragma unroll
    for (int nf = 0; nf < 4; ++nf)
        xv[nf] = *(const ushort4v*)(xlane + (size_t)tx0 * 8192 + nf * 256);
    __syncthreads();   // prologue barrier (full drain OK, once)

    for (int t = 0; t < 32; ++t) {
        int tx  = dir ? 31 - t : t;
        int txn = dir ? 30 - t : t + 1;
        // issue next-step prefetch early (stays in flight across raw barriers)
        if (t < 31) {
#pragma unroll
            for (int nf = 0; nf < 4; ++nf)
                xvn[nf] = *(const ushort4v*)(xlane + (size_t)txn * 8192 + nf * 256);
        }
        short8 afr[4];
#pragma unroll
        for (int kf = 0; kf < 4; ++kf)
            afr[kf] = *(const short8*)&h_lds[lrow * 136 + kf * 32 + kg * 8];
        f32x4 acc[4] = {};
#pragma unroll
        for (int nf = 0; nf < 4; ++nf)
#pragma unroll
            for (int kf = 0; kf < 4; ++kf)
                acc[nf] = __builtin_amdgcn_mfma_f32_16x16x32_bf16(afr[kf], bfr[nf][kf], acc[nf], 0, 0, 0);
#pragma unroll
        for (int nf = 0; nf < 4; ++nf) {
            int g = w * 64 + nf * 16 + lrow;
#pragma unroll
            for (int i = 0; i < 4; ++i)
                gates_lds[(kg * 4 + i) * 516 + g] = acc[nf][i] + bf2f(xv[nf][i]);
        }
        wg_barrier();
        {
            const float* gl = gates_lds + sl * 516 + hq * 4;
            f32x4 gi = *(const f32x4*)(gl);
            f32x4 gf = *(const f32x4*)(gl + 128);
            f32x4 gg = *(const f32x4*)(gl + 256);
            f32x4 go = *(const f32x4*)(gl + 384);
            ushort4v hb;
#pragma unroll
            for (int e = 0; e < 4; ++e) {
                float ci = sigmoidf_(gf[e]) * c[e] + sigmoidf_(gi[e]) * tanhf_(gg[e]);
                c[e] = ci;
                hb[e] = f2bf(sigmoidf_(go[e]) * tanhf_(ci));
            }
            *(ushort4v*)&h_lds[sl * 136 + hq * 4] = hb;
            // store h(tx) into the consumed Xp slot (fire-and-forget)
            *(ushort4v*)(xslot0 + (size_t)tx * 8192 + sl * 128 + hq * 4) = hb;
        }
        wg_barrier();
#pragma unroll
        for (int nf = 0; nf < 4; ++nf) xv[nf] = xvn[nf];
    }
}

// ---------------- FC: feats[t][s][tag] = [hf|hb] @ fcW^T + fcb ----------------
__launch_bounds__(64)
__global__ void k_fc(const unsigned short* Hout, const unsigned short* fcpad,
                     const float* fcb, float* feats)
{
    int t = blockIdx.x, sb = blockIdx.y;
    int lane = threadIdx.x;
    int lrow = lane & 15, kg = lane >> 4;
    f32x4 acc[2] = {};
#pragma unroll
    for (int dir = 0; dir < 2; ++dir) {
        const unsigned short* hb = Hout + ((((size_t)dir * 32 + sb) * 32 + t) << 13) + lrow * 128 + kg * 8;
        const unsigned short* fb = fcpad + dir * 4096 + lrow * 128 + kg * 8;
#pragma unroll
        for (int kf = 0; kf < 4; ++kf) {
            short8 a  = *(const short8*)(hb + kf * 32);
            short8 b0 = *(const short8*)(fb + kf * 32);
            short8 b1 = *(const short8*)(fb + 2048 + kf * 32);
            acc[0] = __builtin_amdgcn_mfma_f32_16x16x32_bf16(a, b0, acc[0], 0, 0, 0);
            acc[1] = __builtin_amdgcn_mfma_f32_16x16x32_bf16(a, b1, acc[1], 0, 0, 0);
        }
    }
#pragma unroll
    for (int nf = 0; nf < 2; ++nf) {
        int tag = nf * 16 + lrow;
        if (tag < NT) {
            float bias = fcb[tag];
#pragma unroll
            for (int i = 0; i < 4; ++i)
                feats[((size_t)t * NS + sb * 16 + kg * 4 + i) * NT + tag] = acc[nf][i] + bias;
        }
    }
}

// ---------------- CRF: MFMA tree-reduction of transfer matrices ----------------
__device__ __forceinline__ float mm_combine(const unsigned short* Rb, const unsigned short* Tb,
                                            int lane, f32x4 c[2][2])
{
    int lrow = lane & 15, kg = lane >> 4;
    short8 a0 = *(const short8*)(Rb + lrow * 32 + kg * 8);
    short8 a1 = *(const short8*)(Rb + (16 + lrow) * 32 + kg * 8);
    short8 b0 = *(const short8*)(Tb + lrow * 32 + kg * 8);
    short8 b1 = *(const short8*)(Tb + (16 + lrow) * 32 + kg * 8);
    c[0][0] = __builtin_amdgcn_mfma_f32_16x16x32_bf16(a0, b0, c[0][0], 0, 0, 0);
    c[0][1] = __builtin_amdgcn_mfma_f32_16x16x32_bf16(a0, b1, c[0][1], 0, 0, 0);
    c[1][0] = __builtin_amdgcn_mfma_f32_16x16x32_bf16(a1, b0, c[1][0], 0, 0, 0);
    c[1][1] = __builtin_amdgcn_mfma_f32_16x16x32_bf16(a1, b1, c[1][1], 0, 0, 0);
    float mx = 0.f;
#pragma unroll
    for (int ti = 0; ti < 2; ++ti)
#pragma unroll
        for (int tj = 0; tj < 2; ++tj)
#pragma unroll
            for (int i = 0; i < 4; ++i) mx = fmaxf(mx, c[ti][tj][i]);
#pragma unroll
    for (int off = 32; off; off >>= 1) mx = fmaxf(mx, __shfl_xor(mx, off));
    return fmaxf(mx, 1e-30f);
}

__device__ __forceinline__ void write_scaled(unsigned short* outp, bool Rlayout,
                                             int lane, const f32x4 c[2][2], float inv)
{
    int lrow = lane & 15, kg = lane >> 4;
    if (Rlayout) {
#pragma unroll
        for (int ti = 0; ti < 2; ++ti)
#pragma unroll
            for (int tj = 0; tj < 2; ++tj) {
                int cc = tj * 16 + lrow;
#pragma unroll
                for (int i = 0; i < 4; ++i) {
                    int r = ti * 16 + kg * 4 + i;
                    float v = (r < NT && cc < NT) ? c[ti][tj][i] * inv : 0.f;
                    outp[r * 32 + cc] = f2bf(v);
                }
            }
    } else {
#pragma unroll
        for (int ti = 0; ti < 2; ++ti)
#pragma unroll
            for (int tj = 0; tj < 2; ++tj) {
                int cc = tj * 16 + lrow;
                int r0 = ti * 16 + kg * 4;
                ushort4v pk;
#pragma unroll
                for (int i = 0; i < 4; ++i) {
                    int r = r0 + i;
                    float v = (r < NT && cc < NT) ? c[ti][tj][i] * inv : 0.f;
                    pk[i] = f2bf(v);
                }
                *(ushort4v*)(outp + cc * 32 + r0) = pk;
            }
    }
}

__launch_bounds__(256)
__global__ void k_crf1(const float* feats, const float* trans,
                       unsigned short* Mseg, float* lscseg)
{
    __shared__ unsigned short mats[16 * 1024];
    __shared__ float etR[484], etT[484];
    __shared__ float ef[16 * 24];
    __shared__ float lscm[16];
    int seg = blockIdx.x, b = blockIdx.y;
    int tid = threadIdx.x;
    int w = tid >> 6, lane = tid & 63;

    for (int i = tid; i < 484; i += 256) {
        float e = __expf(trans[i]);
        etR[i] = e;
        etT[(i % NT) * NT + (i / NT)] = e;
    }
    for (int i = tid; i < 16 * NT; i += 256) {
        int t = i / NT, j = i % NT;
        ef[t * 24 + j] = __expf(feats[((size_t)b * NS + seg * 16 + t) * NT + j]);
    }
    if (tid < 16) lscm[tid] = 0.f;
    __syncthreads();

    for (int idx = tid; idx < 16 * 1024; idx += 256) {
        int t = idx >> 10, cell = idx & 1023, row = cell >> 5, col = cell & 31;
        float v = 0.f;
        if (row < NT && col < NT) {
            v = (t & 1) ? etR[row * NT + col] * ef[t * 24 + row]
                        : etT[row * NT + col] * ef[t * 24 + col];
        }
        mats[idx] = f2bf(v);
    }
    __syncthreads();

    for (int lvl = 0; lvl < 4; ++lvl) {
        int nP = 8 >> lvl;
        for (int p = w; p < nP; p += 4) {
            int aslot = (2 * p) << lvl, bslot = (2 * p + 1) << lvl;
            f32x4 c[2][2] = {};
            float mx = mm_combine(mats + bslot * 1024, mats + aslot * 1024, lane, c);
            float inv = __builtin_amdgcn_rcpf(mx);
            float nlsc = lscm[aslot] + lscm[bslot] + __logf(mx);
            if (lvl < 3) {
                write_scaled(mats + aslot * 1024, (p & 1) != 0, lane, c, inv);
                if (lane == 0) lscm[aslot] = nlsc;
            } else {
                write_scaled(Mseg + ((size_t)b * 32 + seg) * 1024, (seg & 1) != 0, lane, c, inv);
                if (lane == 0) lscseg[b * 32 + seg] = nlsc;
            }
        }
        __syncthreads();
    }
}

__launch_bounds__(256)
__global__ void k_crf2(const unsigned short* Mseg, const float* lscseg,
                       const float* feats, const float* trans, const int* Y,
                       float* fwd_sc, float* gold_sc)
{
    __shared__ unsigned short mats[16 * 1024];
    __shared__ float lscm[16];
    __shared__ float tl[484];
    __shared__ float col20[32];
    __shared__ float red[4];
    int b = blockIdx.x;
    int tid = threadIdx.x;
    int w = tid >> 6, lane = tid & 63;
    int lrow = lane & 15, kg = lane >> 4;

    for (int i = tid; i < 484; i += 256) tl[i] = trans[i];
    __syncthreads();

    const unsigned short* base = Mseg + (size_t)b * 32 * 1024;
    for (int p = w; p < 16; p += 4) {
        f32x4 c[2][2] = {};
        float mx = mm_combine(base + (2 * p + 1) * 1024, base + (2 * p) * 1024, lane, c);
        float inv = __builtin_amdgcn_rcpf(mx);
        float nlsc = lscseg[b * 32 + 2 * p] + lscseg[b * 32 + 2 * p + 1] + __logf(mx);
        write_scaled(mats + p * 1024, (p & 1) != 0, lane, c, inv);
        if (lane == 0) lscm[p] = nlsc;
    }
    __syncthreads();

    for (int lvl = 0; lvl < 4; ++lvl) {
        int nP = 8 >> lvl;
        for (int p = w; p < nP; p += 4) {
            int aslot = (2 * p) << lvl, bslot = (2 * p + 1) << lvl;
            f32x4 c[2][2] = {};
            float mx = mm_combine(mats + bslot * 1024, mats + aslot * 1024, lane, c);
            if (lvl < 3) {
                float inv = __builtin_amdgcn_rcpf(mx);
                float nlsc = lscm[aslot] + lscm[bslot] + __logf(mx);
                write_scaled(mats + aslot * 1024, (p & 1) != 0, lane, c, inv);
                if (lane == 0) lscm[aslot] = nlsc;
            } else {
                if (lrow == 4) {
#pragma unroll
                    for (int ti = 0; ti < 2; ++ti)
#pragma unroll
                        for (int i = 0; i < 4; ++i)
                            col20[ti * 16 + kg * 4 + i] = c[ti][1][i];
                }
                if (lane == 0) lscm[0] = lscm[0] + lscm[8];
            }
        }
        __syncthreads();
    }

    if (w == 0) {
        float v = 0.f;
        if (lane < NT) v = __expf(tl[(NT - 1) * NT + lane]) * col20[lane];
#pragma unroll
        for (int off = 32; off; off >>= 1) v += __shfl_xor(v, off);
        if (lane == 0) fwd_sc[b] = __logf(v) + lscm[0];
    }

    const float* fb = feats + (size_t)b * NS * NT;
    float acc = 0.f;
    for (int s = tid; s < NS; s += 256) {
        int y = Y[b * NS + s];
        int yp = s ? Y[b * NS + s - 1] : (NT - 2);
        acc += fb[s * NT + y] + tl[y * NT + yp];
    }
    if (tid == 0) acc += tl[(NT - 1) * NT + Y[b * NS + NS - 1]];
#pragma unroll
    for (int off = 32; off; off >>= 1) acc += __shfl_xor(acc, off);
    if (lane == 0) red[w] = acc;
    __syncthreads();
    if (tid == 0) gold_sc[b] = red[0] + red[1] + red[2] + red[3];
}

// ---------------- final: score + Y copy ----------------
__global__ void k_final(const float* fwd_sc, const float* gold_sc, const int* Y, float* out)
{
    int idx = blockIdx.x * blockDim.x + threadIdx.x;
    if (blockIdx.x == 0 && threadIdx.x < 64) {
        float v = (threadIdx.x < NB) ? (fwd_sc[threadIdx.x] - gold_sc[threadIdx.x]) : 0.f;
#pragma unroll
        for (int off = 32; off; off >>= 1) v += __shfl_xor(v, off);
        if (threadIdx.x == 0) out[0] = v * (1.f / NB);
    }
    if (idx < NB * NS) out[1 + idx] = (float)Y[idx];
}

extern "C" void kernel_launch(void* const* d_in, const int* in_sizes, int n_in,
                              void* d_out, int out_size, void* d_ws, size_t ws_size,
                              hipStream_t stream)
{
    const int* X = (const int*)d_in[0];
    const int* Y = (const int*)d_in[1];
    const float* emb = (const float*)d_in[2];
    const float* Wih_f = (const float*)d_in[3];
    const float* Whh_f = (const float*)d_in[4];
    const float* bih_f = (const float*)d_in[5];
    const float* bhh_f = (const float*)d_in[6];
    const float* Wih_b = (const float*)d_in[7];
    const float* Whh_b = (const float*)d_in[8];
    const float* bih_b = (const float*)d_in[9];
    const float* bhh_b = (const float*)d_in[10];
    const float* fcW = (const float*)d_in[11];
    const float* fcb = (const float*)d_in[12];
    const float* trans = (const float*)d_in[13];
    const float* h0 = (const float*)d_in[14];
    const float* c0 = (const float*)d_in[15];
    float* out = (float*)d_out;

    char* ws = (char*)d_ws;
    unsigned short* Wb_ih = (unsigned short*)(ws + 0);          // 524288 B
    unsigned short* Wb_hh = (unsigned short*)(ws + 524288);     // 262144 B
    unsigned short* fcpad = (unsigned short*)(ws + 786432);     // 16384 B
    unsigned short* Xp    = (unsigned short*)(ws + 802816);     // 33554432 B (doubles as Hout)
    float* feats          = (float*)(ws + 34357248);            // 1441792 B
    float* fwd_sc         = (float*)(ws + 35799040);            // 128 B
    float* gold_sc        = (float*)(ws + 35799168);            // 128 B
    unsigned short* ebf   = (unsigned short*)(ws + 35799296);   // 8388608 B
    unsigned short* Mseg  = ebf;                                // 2097152 B (ebf dead after k_xproj)
    float* lscseg         = (float*)(ws + 35799296 + 2097152);  // 4096 B

    k_prep<<<dim3(1568), dim3(256), 0, stream>>>(Wih_f, Wih_b, Whh_f, Whh_b, fcW,
                                                 Wb_ih, Wb_hh, fcpad);
    k_embcvt<<<dim3(NB * NS), dim3(64), 0, stream>>>(X, emb, ebf);
    k_xproj<<<dim3(256, 8, 2), dim3(256), 0, stream>>>(ebf, Wb_ih, bih_f, bhh_f, bih_b, bhh_b, Xp);
    k_lstm<<<dim3(64), dim3(512), 0, stream>>>(Wb_hh, Xp, h0, c0);
    k_fc<<<dim3(32, 32), dim3(64), 0, stream>>>(Xp, fcpad, fcb, feats);
    k_crf1<<<dim3(32, 32), dim3(256), 0, stream>>>(feats, trans, Mseg, lscseg);
    k_crf2<<<dim3(NB), dim3(256), 0, stream>>>(Mseg, lscseg, feats, trans, Y, fwd_sc, gold_sc);
    k_final<<<dim3(64), dim3(256), 0, stream>>>(fwd_sc, gold_sc, Y, out);
    (void)in_sizes; (void)n_in; (void)out_size; (void)ws_size;
}

// Round 6
// 110.011 us; speedup vs baseline: 2.6493x; 1.3890x over previous
//
#include <hip/hip_runtime.h>
#include <hip/hip_bf16.h>
#include <stdint.h>

typedef __attribute__((ext_vector_type(8))) short short8;
typedef __attribute__((ext_vector_type(4))) float f32x4;
typedef __attribute__((ext_vector_type(4))) unsigned short ushort4v;

#define NB 32
#define NS 512
#define NE 256
#define NH2 128
#define NG 512
#define NT 22

__device__ __forceinline__ unsigned short f2bf(float f) {
    union { float f; unsigned u; } v; v.f = f;
    unsigned r = v.u + 0x7fffu + ((v.u >> 16) & 1u);
    return (unsigned short)(r >> 16);
}
__device__ __forceinline__ float bf2f(unsigned short b) {
    union { unsigned u; float f; } v; v.u = ((unsigned)b) << 16;
    return v.f;
}
__device__ __forceinline__ float sigmoidf_(float x) {
    return __builtin_amdgcn_rcpf(1.f + __expf(-x));
}
__device__ __forceinline__ float tanhf_(float x) {
    return 1.f - 2.f * __builtin_amdgcn_rcpf(__expf(2.f * x) + 1.f);
}
// raw workgroup barrier: LDS-only ordering, leaves global loads/stores in flight
__device__ __forceinline__ void wg_barrier() {
    __builtin_amdgcn_sched_barrier(0);
    asm volatile("s_waitcnt lgkmcnt(0)" ::: "memory");
    __builtin_amdgcn_s_barrier();
    __builtin_amdgcn_sched_barrier(0);
}
// async global->LDS: wave-uniform LDS base, per-lane global src, 16B/lane
#define GL16(gsrc, ldst)                                                              \
    __builtin_amdgcn_global_load_lds(                                                 \
        (const __attribute__((address_space(1))) unsigned int*)(gsrc),                \
        (__attribute__((address_space(3))) unsigned int*)(ldst), 16, 0, 0)

// ---------------- prep: weight conversions ----------------
__global__ void k_prep(const float* Wih_f, const float* Wih_b,
                       const float* Whh_f, const float* Whh_b,
                       const float* fcW,
                       unsigned short* Wb_ih, unsigned short* Wb_hh,
                       unsigned short* fcpad)
{
    int idx = blockIdx.x * blockDim.x + threadIdx.x;
    const int n1 = 2 * NG * NE;     // 262144
    const int n2 = 2 * NG * NH2;    // 131072
    const int n3 = 2 * 32 * NH2;    // 8192
    if (idx < n1) {
        const float* src = (idx < NG * NE) ? Wih_f : Wih_b;
        Wb_ih[idx] = f2bf(src[idx % (NG * NE)]);
    } else if (idx < n1 + n2) {
        int i2 = idx - n1;
        const float* src = (i2 < NG * NH2) ? Whh_f : Whh_b;
        Wb_hh[i2] = f2bf(src[i2 % (NG * NH2)]);
    } else if (idx < n1 + n2 + n3) {
        int i3 = idx - n1 - n2;
        int d = i3 / (32 * NH2);
        int j = (i3 / NH2) % 32;
        int k = i3 % NH2;
        fcpad[i3] = (j < NT) ? f2bf(fcW[j * 256 + d * NH2 + k]) : (unsigned short)0;
    }
}

// ---------------- embedding gather + bf16 convert ----------------
__global__ void k_embcvt(const int* X, const float* emb, unsigned short* ebf)
{
    int r = blockIdx.x * 4 + (threadIdx.x >> 6);   // 16384 rows
    int lane = threadIdx.x & 63;
    int xr = X[r];
    f32x4 v = *(const f32x4*)(emb + (size_t)xr * NE + lane * 4);
    ushort4v o;
    o[0] = f2bf(v[0]); o[1] = f2bf(v[1]); o[2] = f2bf(v[2]); o[3] = f2bf(v[3]);
    *(ushort4v*)(ebf + (size_t)r * NE + lane * 4) = o;
}

// ---------------- input projection GEMM: m97-style LDS-staged 128x128 tile ----------------
// C[r][g] = ebf[r][:] . Wb_ih[g][:] + bias, written to block-local Xp layout
// Xp[dir][sb(32)][t(32)][g(512)][16 s]  (slot = 8192 bf16 = 16KB)
__launch_bounds__(256)
__global__ void k_xproj(const unsigned short* ebf, const unsigned short* Wb_ih,
                        const float* bih_f, const float* bhh_f,
                        const float* bih_b, const float* bhh_b,
                        unsigned short* Xp)
{
    __shared__ __align__(16) unsigned short Atile[128 * 64];   // 16KB
    __shared__ __align__(16) unsigned short Btile[128 * 64];   // 16KB
    int dir = blockIdx.z;
    int r0 = blockIdx.x * 128;
    int g0 = blockIdx.y * 128;
    int tid = threadIdx.x;
    int w = tid >> 6, lane = tid & 63;
    int wr = w >> 1, wc = w & 1;
    int lrow = lane & 15, kg = lane >> 4;
    int srow8 = lane >> 3, schunk = lane & 7;    // staging: 8 rows/call, 8 chunks/row
    const float* bih = dir ? bih_b : bih_f;
    const float* bhh = dir ? bhh_b : bhh_f;
    const unsigned short* Bsrc = Wb_ih + ((size_t)dir * NG + g0) * NE;
    const unsigned short* Asrc = ebf + (size_t)r0 * NE;

    f32x4 acc[4][4] = {};
#pragma unroll
    for (int ks = 0; ks < 4; ++ks) {
        int k0 = ks * 64;
        // stage A,B tiles: 8 global_load_lds_dwordx4 per wave (1KB LDS each)
#pragma unroll
        for (int i = 0; i < 4; ++i) {
            int rr = (w * 4 + i) * 8 + srow8;
            GL16(Asrc + (size_t)rr * NE + k0 + schunk * 8, Atile + (w * 4 + i) * 512);
            GL16(Bsrc + (size_t)rr * NE + k0 + schunk * 8, Btile + (w * 4 + i) * 512);
        }
        __syncthreads();   // drains staging (vmcnt) + LDS
        short8 a[4][2], b[4][2];
#pragma unroll
        for (int mi = 0; mi < 4; ++mi)
#pragma unroll
            for (int kk = 0; kk < 2; ++kk)
                a[mi][kk] = *(const short8*)&Atile[(wr * 64 + mi * 16 + lrow) * 64 + kk * 32 + kg * 8];
#pragma unroll
        for (int ni = 0; ni < 4; ++ni)
#pragma unroll
            for (int kk = 0; kk < 2; ++kk)
                b[ni][kk] = *(const short8*)&Btile[(wc * 64 + ni * 16 + lrow) * 64 + kk * 32 + kg * 8];
#pragma unroll
        for (int mi = 0; mi < 4; ++mi)
#pragma unroll
            for (int ni = 0; ni < 4; ++ni)
#pragma unroll
                for (int kk = 0; kk < 2; ++kk)
                    acc[mi][ni] = __builtin_amdgcn_mfma_f32_16x16x32_bf16(a[mi][kk], b[ni][kk], acc[mi][ni], 0, 0, 0);
        __syncthreads();   // all reads done before next restage
    }

#pragma unroll
    for (int ni = 0; ni < 4; ++ni) {
        int g = g0 + wc * 64 + ni * 16 + lrow;
        float bias = bih[g] + bhh[g];
#pragma unroll
        for (int mi = 0; mi < 4; ++mi) {
            int r = r0 + wr * 64 + mi * 16 + kg * 4;
            int t = r >> 9;              // r / 512
            int s = r & 511;
            int sb = s >> 4;
            unsigned short* dst = Xp + ((((size_t)dir * 32 + sb) * 32 + t) << 13) + g * 16 + (s & 15);
            unsigned o0 = f2bf(acc[mi][ni][0] + bias);
            unsigned o1 = f2bf(acc[mi][ni][1] + bias);
            unsigned o2 = f2bf(acc[mi][ni][2] + bias);
            unsigned o3 = f2bf(acc[mi][ni][3] + bias);
            uint2 pk; pk.x = o0 | (o1 << 16); pk.y = o2 | (o3 << 16);
            *(uint2*)dst = pk;
        }
    }
}

// ---------------- LSTM recurrence (32 steps), barrier-light, prefetched ----------------
// h(t) is stored (bf16) into the just-consumed Xp slot (dir,sb,tx):
//   Hout(dir,sb,tx) = Xp + slot*8192, chunk [16 s][128 d].
__launch_bounds__(512, 2)
__global__ void k_lstm(const unsigned short* Wb_hh, unsigned short* Xp,
                       const float* h0, const float* c0)
{
    __shared__ unsigned short h_lds[16 * 136];
    __shared__ float gates_lds[16 * 516];
    int dir = blockIdx.x >> 5;
    int sb = blockIdx.x & 31;
    int s0 = sb * 16;
    int tid = threadIdx.x;
    int w = tid >> 6, lane = tid & 63;
    int lrow = lane & 15, kg = lane >> 4;
    int sl = tid >> 5, hq = tid & 31;

    short8 bfr[4][4];
#pragma unroll
    for (int nf = 0; nf < 4; ++nf) {
        const unsigned short* p = Wb_hh + ((size_t)dir * NG + (w * 64 + nf * 16 + lrow)) * NH2 + kg * 8;
#pragma unroll
        for (int kf = 0; kf < 4; ++kf)
            bfr[nf][kf] = *(const short8*)(p + kf * 32);
    }

    float c[4];
    {
        f32x4 cv = *(const f32x4*)(c0 + ((size_t)dir * NS + s0 + sl) * NH2 + hq * 4);
        c[0] = cv[0]; c[1] = cv[1]; c[2] = cv[2]; c[3] = cv[3];
        f32x4 hv = *(const f32x4*)(h0 + ((size_t)dir * NS + s0 + sl) * NH2 + hq * 4);
        ushort4v hb; hb[0] = f2bf(hv[0]); hb[1] = f2bf(hv[1]); hb[2] = f2bf(hv[2]); hb[3] = f2bf(hv[3]);
        *(ushort4v*)&h_lds[sl * 136 + hq * 4] = hb;
    }

    // prologue prefetch: Xp(tx0), per-wave contiguous 2KB chunk
    unsigned short* xslot0 = Xp + (((size_t)dir * 32 + sb) * 32) * 8192;
    const unsigned short* xlane = xslot0 + (w * 64 + lrow) * 16 + kg * 4;
    int tx0 = dir ? 31 : 0;
    ushort4v xv[4], xvn[4];
#pragma unroll
    for (int nf = 0; nf < 4; ++nf)
        xv[nf] = *(const ushort4v*)(xlane + (size_t)tx0 * 8192 + nf * 256);
    __syncthreads();   // prologue barrier (full drain OK, once)

    for (int t = 0; t < 32; ++t) {
        int tx  = dir ? 31 - t : t;
        int txn = dir ? 30 - t : t + 1;
        // issue next-step prefetch early (stays in flight across raw barriers)
        if (t < 31) {
#pragma unroll
            for (int nf = 0; nf < 4; ++nf)
                xvn[nf] = *(const ushort4v*)(xlane + (size_t)txn * 8192 + nf * 256);
        }
        short8 afr[4];
#pragma unroll
        for (int kf = 0; kf < 4; ++kf)
            afr[kf] = *(const short8*)&h_lds[lrow * 136 + kf * 32 + kg * 8];
        f32x4 acc[4] = {};
#pragma unroll
        for (int nf = 0; nf < 4; ++nf)
#pragma unroll
            for (int kf = 0; kf < 4; ++kf)
                acc[nf] = __builtin_amdgcn_mfma_f32_16x16x32_bf16(afr[kf], bfr[nf][kf], acc[nf], 0, 0, 0);
#pragma unroll
        for (int nf = 0; nf < 4; ++nf) {
            int g = w * 64 + nf * 16 + lrow;
#pragma unroll
            for (int i = 0; i < 4; ++i)
                gates_lds[(kg * 4 + i) * 516 + g] = acc[nf][i] + bf2f(xv[nf][i]);
        }
        wg_barrier();
        {
            const float* gl = gates_lds + sl * 516 + hq * 4;
            f32x4 gi = *(const f32x4*)(gl);
            f32x4 gf = *(const f32x4*)(gl + 128);
            f32x4 gg = *(const f32x4*)(gl + 256);
            f32x4 go = *(const f32x4*)(gl + 384);
            ushort4v hb;
#pragma unroll
            for (int e = 0; e < 4; ++e) {
                float ci = sigmoidf_(gf[e]) * c[e] + sigmoidf_(gi[e]) * tanhf_(gg[e]);
                c[e] = ci;
                hb[e] = f2bf(sigmoidf_(go[e]) * tanhf_(ci));
            }
            *(ushort4v*)&h_lds[sl * 136 + hq * 4] = hb;
            // store h(tx) into the consumed Xp slot (fire-and-forget)
            *(ushort4v*)(xslot0 + (size_t)tx * 8192 + sl * 128 + hq * 4) = hb;
        }
        wg_barrier();
#pragma unroll
        for (int nf = 0; nf < 4; ++nf) xv[nf] = xvn[nf];
    }
}

// ---------------- FC: feats[t][s][tag] = [hf|hb] @ fcW^T + fcb ----------------
// 2 waves per block: wave = dir; cross-dir reduce via LDS.
__launch_bounds__(128)
__global__ void k_fc(const unsigned short* Hout, const unsigned short* fcpad,
                     const float* fcb, float* feats)
{
    __shared__ f32x4 part[2][64];
    int t = blockIdx.x, sb = blockIdx.y;
    int tid = threadIdx.x;
    int dir = tid >> 6, lane = tid & 63;
    int lrow = lane & 15, kg = lane >> 4;
    const unsigned short* hb = Hout + ((((size_t)dir * 32 + sb) * 32 + t) << 13) + lrow * 128 + kg * 8;
    const unsigned short* fb = fcpad + dir * 4096 + lrow * 128 + kg * 8;
    f32x4 acc[2] = {};
#pragma unroll
    for (int kf = 0; kf < 4; ++kf) {
        short8 a  = *(const short8*)(hb + kf * 32);
        short8 b0 = *(const short8*)(fb + kf * 32);
        short8 b1 = *(const short8*)(fb + 2048 + kf * 32);
        acc[0] = __builtin_amdgcn_mfma_f32_16x16x32_bf16(a, b0, acc[0], 0, 0, 0);
        acc[1] = __builtin_amdgcn_mfma_f32_16x16x32_bf16(a, b1, acc[1], 0, 0, 0);
    }
    if (dir == 1) { part[0][lane] = acc[0]; part[1][lane] = acc[1]; }
    __syncthreads();
    if (dir == 0) {
        acc[0] += part[0][lane];
        acc[1] += part[1][lane];
#pragma unroll
        for (int nf = 0; nf < 2; ++nf) {
            int tag = nf * 16 + lrow;
            if (tag < NT) {
                float bias = fcb[tag];
#pragma unroll
                for (int i = 0; i < 4; ++i)
                    feats[((size_t)t * NS + sb * 16 + kg * 4 + i) * NT + tag] = acc[nf][i] + bias;
            }
        }
    }
}

// ---------------- CRF: MFMA tree-reduction of transfer matrices ----------------
__device__ __forceinline__ float mm_combine(const unsigned short* Rb, const unsigned short* Tb,
                                            int lane, f32x4 c[2][2])
{
    int lrow = lane & 15, kg = lane >> 4;
    short8 a0 = *(const short8*)(Rb + lrow * 32 + kg * 8);
    short8 a1 = *(const short8*)(Rb + (16 + lrow) * 32 + kg * 8);
    short8 b0 = *(const short8*)(Tb + lrow * 32 + kg * 8);
    short8 b1 = *(const short8*)(Tb + (16 + lrow) * 32 + kg * 8);
    c[0][0] = __builtin_amdgcn_mfma_f32_16x16x32_bf16(a0, b0, c[0][0], 0, 0, 0);
    c[0][1] = __builtin_amdgcn_mfma_f32_16x16x32_bf16(a0, b1, c[0][1], 0, 0, 0);
    c[1][0] = __builtin_amdgcn_mfma_f32_16x16x32_bf16(a1, b0, c[1][0], 0, 0, 0);
    c[1][1] = __builtin_amdgcn_mfma_f32_16x16x32_bf16(a1, b1, c[1][1], 0, 0, 0);
    float mx = 0.f;
#pragma unroll
    for (int ti = 0; ti < 2; ++ti)
#pragma unroll
        for (int tj = 0; tj < 2; ++tj)
#pragma unroll
            for (int i = 0; i < 4; ++i) mx = fmaxf(mx, c[ti][tj][i]);
#pragma unroll
    for (int off = 32; off; off >>= 1) mx = fmaxf(mx, __shfl_xor(mx, off));
    return fmaxf(mx, 1e-30f);
}

__device__ __forceinline__ void write_scaled(unsigned short* outp, bool Rlayout,
                                             int lane, const f32x4 c[2][2], float inv)
{
    int lrow = lane & 15, kg = lane >> 4;
    if (Rlayout) {
#pragma unroll
        for (int ti = 0; ti < 2; ++ti)
#pragma unroll
            for (int tj = 0; tj < 2; ++tj) {
                int cc = tj * 16 + lrow;
#pragma unroll
                for (int i = 0; i < 4; ++i) {
                    int r = ti * 16 + kg * 4 + i;
                    float v = (r < NT && cc < NT) ? c[ti][tj][i] * inv : 0.f;
                    outp[r * 32 + cc] = f2bf(v);
                }
            }
    } else {
#pragma unroll
        for (int ti = 0; ti < 2; ++ti)
#pragma unroll
            for (int tj = 0; tj < 2; ++tj) {
                int cc = tj * 16 + lrow;
                int r0 = ti * 16 + kg * 4;
                ushort4v pk;
#pragma unroll
                for (int i = 0; i < 4; ++i) {
                    int r = r0 + i;
                    float v = (r < NT && cc < NT) ? c[ti][tj][i] * inv : 0.f;
                    pk[i] = f2bf(v);
                }
                *(ushort4v*)(outp + cc * 32 + r0) = pk;
            }
    }
}

__launch_bounds__(256)
__global__ void k_crf1(const float* feats, const float* trans,
                       unsigned short* Mseg, float* lscseg)
{
    __shared__ unsigned short mats[16 * 1024];
    __shared__ float etR[484], etT[484];
    __shared__ float ef[16 * 24];
    __shared__ float lscm[16];
    int seg = blockIdx.x, b = blockIdx.y;
    int tid = threadIdx.x;
    int w = tid >> 6, lane = tid & 63;

    for (int i = tid; i < 484; i += 256) {
        float e = __expf(trans[i]);
        etR[i] = e;
        etT[(i % NT) * NT + (i / NT)] = e;
    }
    for (int i = tid; i < 16 * NT; i += 256) {
        int t = i / NT, j = i % NT;
        ef[t * 24 + j] = __expf(feats[((size_t)b * NS + seg * 16 + t) * NT + j]);
    }
    if (tid < 16) lscm[tid] = 0.f;
    __syncthreads();

    for (int idx = tid; idx < 16 * 1024; idx += 256) {
        int t = idx >> 10, cell = idx & 1023, row = cell >> 5, col = cell & 31;
        float v = 0.f;
        if (row < NT && col < NT) {
            v = (t & 1) ? etR[row * NT + col] * ef[t * 24 + row]
                        : etT[row * NT + col] * ef[t * 24 + col];
        }
        mats[idx] = f2bf(v);
    }
    __syncthreads();

    for (int lvl = 0; lvl < 4; ++lvl) {
        int nP = 8 >> lvl;
        for (int p = w; p < nP; p += 4) {
            int aslot = (2 * p) << lvl, bslot = (2 * p + 1) << lvl;
            f32x4 c[2][2] = {};
            float mx = mm_combine(mats + bslot * 1024, mats + aslot * 1024, lane, c);
            float inv = __builtin_amdgcn_rcpf(mx);
            float nlsc = lscm[aslot] + lscm[bslot] + __logf(mx);
            if (lvl < 3) {
                write_scaled(mats + aslot * 1024, (p & 1) != 0, lane, c, inv);
                if (lane == 0) lscm[aslot] = nlsc;
            } else {
                write_scaled(Mseg + ((size_t)b * 32 + seg) * 1024, (seg & 1) != 0, lane, c, inv);
                if (lane == 0) lscseg[b * 32 + seg] = nlsc;
            }
        }
        __syncthreads();
    }
}

__launch_bounds__(256)
__global__ void k_crf2(const unsigned short* Mseg, const float* lscseg,
                       const float* feats, const float* trans, const int* Y,
                       float* fwd_sc, float* gold_sc)
{
    __shared__ unsigned short mats[16 * 1024];
    __shared__ float lscm[16];
    __shared__ float tl[484];
    __shared__ float col20[32];
    __shared__ float red[4];
    int b = blockIdx.x;
    int tid = threadIdx.x;
    int w = tid >> 6, lane = tid & 63;
    int lrow = lane & 15, kg = lane >> 4;

    for (int i = tid; i < 484; i += 256) tl[i] = trans[i];
    __syncthreads();

    const unsigned short* base = Mseg + (size_t)b * 32 * 1024;
    for (int p = w; p < 16; p += 4) {
        f32x4 c[2][2] = {};
        float mx = mm_combine(base + (2 * p + 1) * 1024, base + (2 * p) * 1024, lane, c);
        float inv = __builtin_amdgcn_rcpf(mx);
        float nlsc = lscseg[b * 32 + 2 * p] + lscseg[b * 32 + 2 * p + 1] + __logf(mx);
        write_scaled(mats + p * 1024, (p & 1) != 0, lane, c, inv);
        if (lane == 0) lscm[p] = nlsc;
    }
    __syncthreads();

    for (int lvl = 0; lvl < 4; ++lvl) {
        int nP = 8 >> lvl;
        for (int p = w; p < nP; p += 4) {
            int aslot = (2 * p) << lvl, bslot = (2 * p + 1) << lvl;
            f32x4 c[2][2] = {};
            float mx = mm_combine(mats + bslot * 1024, mats + aslot * 1024, lane, c);
            if (lvl < 3) {
                float inv = __builtin_amdgcn_rcpf(mx);
                float nlsc = lscm[aslot] + lscm[bslot] + __logf(mx);
                write_scaled(mats + aslot * 1024, (p & 1) != 0, lane, c, inv);
                if (lane == 0) lscm[aslot] = nlsc;
            } else {
                if (lrow == 4) {
#pragma unroll
                    for (int ti = 0; ti < 2; ++ti)
#pragma unroll
                        for (int i = 0; i < 4; ++i)
                            col20[ti * 16 + kg * 4 + i] = c[ti][1][i];
                }
                if (lane == 0) lscm[0] = lscm[0] + lscm[8];
            }
        }
        __syncthreads();
    }

    if (w == 0) {
        float v = 0.f;
        if (lane < NT) v = __expf(tl[(NT - 1) * NT + lane]) * col20[lane];
#pragma unroll
        for (int off = 32; off; off >>= 1) v += __shfl_xor(v, off);
        if (lane == 0) fwd_sc[b] = __logf(v) + lscm[0];
    }

    const float* fb = feats + (size_t)b * NS * NT;
    float acc = 0.f;
    for (int s = tid; s < NS; s += 256) {
        int y = Y[b * NS + s];
        int yp = s ? Y[b * NS + s - 1] : (NT - 2);
        acc += fb[s * NT + y] + tl[y * NT + yp];
    }
    if (tid == 0) acc += tl[(NT - 1) * NT + Y[b * NS + NS - 1]];
#pragma unroll
    for (int off = 32; off; off >>= 1) acc += __shfl_xor(acc, off);
    if (lane == 0) red[w] = acc;
    __syncthreads();
    if (tid == 0) gold_sc[b] = red[0] + red[1] + red[2] + red[3];
}

// ---------------- final: score + Y copy ----------------
__global__ void k_final(const float* fwd_sc, const float* gold_sc, const int* Y, float* out)
{
    int idx = blockIdx.x * blockDim.x + threadIdx.x;
    if (blockIdx.x == 0 && threadIdx.x < 64) {
        float v = (threadIdx.x < NB) ? (fwd_sc[threadIdx.x] - gold_sc[threadIdx.x]) : 0.f;
#pragma unroll
        for (int off = 32; off; off >>= 1) v += __shfl_xor(v, off);
        if (threadIdx.x == 0) out[0] = v * (1.f / NB);
    }
    if (idx < NB * NS) out[1 + idx] = (float)Y[idx];
}

extern "C" void kernel_launch(void* const* d_in, const int* in_sizes, int n_in,
                              void* d_out, int out_size, void* d_ws, size_t ws_size,
                              hipStream_t stream)
{
    const int* X = (const int*)d_in[0];
    const int* Y = (const int*)d_in[1];
    const float* emb = (const float*)d_in[2];
    const float* Wih_f = (const float*)d_in[3];
    const float* Whh_f = (const float*)d_in[4];
    const float* bih_f = (const float*)d_in[5];
    const float* bhh_f = (const float*)d_in[6];
    const float* Wih_b = (const float*)d_in[7];
    const float* Whh_b = (const float*)d_in[8];
    const float* bih_b = (const float*)d_in[9];
    const float* bhh_b = (const float*)d_in[10];
    const float* fcW = (const float*)d_in[11];
    const float* fcb = (const float*)d_in[12];
    const float* trans = (const float*)d_in[13];
    const float* h0 = (const float*)d_in[14];
    const float* c0 = (const float*)d_in[15];
    float* out = (float*)d_out;

    char* ws = (char*)d_ws;
    unsigned short* Wb_ih = (unsigned short*)(ws + 0);          // 524288 B
    unsigned short* Wb_hh = (unsigned short*)(ws + 524288);     // 262144 B
    unsigned short* fcpad = (unsigned short*)(ws + 786432);     // 16384 B
    unsigned short* Xp    = (unsigned short*)(ws + 802816);     // 33554432 B (doubles as Hout)
    float* feats          = (float*)(ws + 34357248);            // 1441792 B
    float* fwd_sc         = (float*)(ws + 35799040);            // 128 B
    float* gold_sc        = (float*)(ws + 35799168);            // 128 B
    unsigned short* ebf   = (unsigned short*)(ws + 35799296);   // 8388608 B
    unsigned short* Mseg  = ebf;                                // 2097152 B (ebf dead after k_xproj)
    float* lscseg         = (float*)(ws + 35799296 + 2097152);  // 4096 B

    k_prep<<<dim3(1568), dim3(256), 0, stream>>>(Wih_f, Wih_b, Whh_f, Whh_b, fcW,
                                                 Wb_ih, Wb_hh, fcpad);
    k_embcvt<<<dim3(4096), dim3(256), 0, stream>>>(X, emb, ebf);
    k_xproj<<<dim3(128, 4, 2), dim3(256), 0, stream>>>(ebf, Wb_ih, bih_f, bhh_f, bih_b, bhh_b, Xp);
    k_lstm<<<dim3(64), dim3(512), 0, stream>>>(Wb_hh, Xp, h0, c0);
    k_fc<<<dim3(32, 32), dim3(128), 0, stream>>>(Xp, fcpad, fcb, feats);
    k_crf1<<<dim3(32, 32), dim3(256), 0, stream>>>(feats, trans, Mseg, lscseg);
    k_crf2<<<dim3(NB), dim3(256), 0, stream>>>(Mseg, lscseg, feats, trans, Y, fwd_sc, gold_sc);
    k_final<<<dim3(64), dim3(256), 0, stream>>>(fwd_sc, gold_sc, Y, out);
    (void)in_sizes; (void)n_in; (void)out_size; (void)ws_size;
}

// Round 7
// 97.652 us; speedup vs baseline: 2.9846x; 1.1266x over previous
//
#include <hip/hip_runtime.h>
#include <hip/hip_bf16.h>
#include <stdint.h>

typedef __attribute__((ext_vector_type(8))) short short8;
typedef __attribute__((ext_vector_type(4))) float f32x4;
typedef __attribute__((ext_vector_type(4))) unsigned short ushort4v;

#define NB 32
#define NS 512
#define NE 256
#define NH2 128
#define NG 512
#define NT 22

__device__ __forceinline__ unsigned short f2bf(float f) {
    union { float f; unsigned u; } v; v.f = f;
    unsigned r = v.u + 0x7fffu + ((v.u >> 16) & 1u);
    return (unsigned short)(r >> 16);
}
__device__ __forceinline__ float bf2f(unsigned short b) {
    union { unsigned u; float f; } v; v.u = ((unsigned)b) << 16;
    return v.f;
}
__device__ __forceinline__ float sigmoidf_(float x) {
    return __builtin_amdgcn_rcpf(1.f + __expf(-x));
}
__device__ __forceinline__ float tanhf_(float x) {
    return 1.f - 2.f * __builtin_amdgcn_rcpf(__expf(2.f * x) + 1.f);
}
// raw workgroup barrier: LDS-only ordering, leaves global loads/stores in flight
__device__ __forceinline__ void wg_barrier() {
    __builtin_amdgcn_sched_barrier(0);
    asm volatile("s_waitcnt lgkmcnt(0)" ::: "memory");
    __builtin_amdgcn_s_barrier();
    __builtin_amdgcn_sched_barrier(0);
}
// async global->LDS: wave-uniform LDS base, per-lane global src, 16B/lane
#define GL16(gsrc, ldst)                                                              \
    __builtin_amdgcn_global_load_lds(                                                 \
        (const __attribute__((address_space(1))) unsigned int*)(gsrc),                \
        (__attribute__((address_space(3))) unsigned int*)(ldst), 16, 0, 0)

// ---------------- pre: emb gather+cvt, weight conversions, Y copy ----------------
__global__ void k_pre(const int* X, const float* emb, const int* Y,
                      const float* Wih_f, const float* Wih_b,
                      const float* Whh_f, const float* Whh_b, const float* fcW,
                      unsigned short* ebf, unsigned short* Wb_ih,
                      unsigned short* Wb_hh, unsigned short* fcpad, float* out)
{
    int idx = blockIdx.x * blockDim.x + threadIdx.x;
    const int nEmb = NB * NS * 64;          // 1048576 lane-tasks
    if (idx < nEmb) {
        int r = idx >> 6, lane = idx & 63;
        int xr = X[r];
        f32x4 v = *(const f32x4*)(emb + (size_t)xr * NE + lane * 4);
        ushort4v o;
        o[0] = f2bf(v[0]); o[1] = f2bf(v[1]); o[2] = f2bf(v[2]); o[3] = f2bf(v[3]);
        *(ushort4v*)(ebf + (size_t)r * NE + lane * 4) = o;
        return;
    }
    int j = idx - nEmb;
    const int n1 = 2 * NG * NE;     // 262144
    const int n2 = 2 * NG * NH2;    // 131072
    const int n3 = 2 * 32 * NH2;    // 8192
    const int n4 = NB * NS;         // 16384
    if (j < n1) {
        const float* src = (j < NG * NE) ? Wih_f : Wih_b;
        Wb_ih[j] = f2bf(src[j % (NG * NE)]);
    } else if (j < n1 + n2) {
        int i2 = j - n1;
        const float* src = (i2 < NG * NH2) ? Whh_f : Whh_b;
        Wb_hh[i2] = f2bf(src[i2 % (NG * NH2)]);
    } else if (j < n1 + n2 + n3) {
        int i3 = j - n1 - n2;
        int d = i3 / (32 * NH2);
        int jj = (i3 / NH2) % 32;
        int k = i3 % NH2;
        fcpad[i3] = (jj < NT) ? f2bf(fcW[jj * 256 + d * NH2 + k]) : (unsigned short)0;
    } else if (j < n1 + n2 + n3 + n4) {
        int i4 = j - n1 - n2 - n3;
        out[1 + i4] = (float)Y[i4];
    }
}

// ---------------- input projection GEMM: LDS-staged 128x128 tile ----------------
// Xp[dir][sb(32)][t(32)][g(512)][16 s]  (slot = 8192 bf16 = 16KB)
__launch_bounds__(256)
__global__ void k_xproj(const unsigned short* ebf, const unsigned short* Wb_ih,
                        const float* bih_f, const float* bhh_f,
                        const float* bih_b, const float* bhh_b,
                        unsigned short* Xp)
{
    __shared__ __align__(16) unsigned short Atile[128 * 64];   // 16KB
    __shared__ __align__(16) unsigned short Btile[128 * 64];   // 16KB
    int dir = blockIdx.z;
    int r0 = blockIdx.x * 128;
    int g0 = blockIdx.y * 128;
    int tid = threadIdx.x;
    int w = tid >> 6, lane = tid & 63;
    int wr = w >> 1, wc = w & 1;
    int lrow = lane & 15, kg = lane >> 4;
    int srow8 = lane >> 3, schunk = lane & 7;    // staging: 8 rows/call, 8 chunks/row
    const float* bih = dir ? bih_b : bih_f;
    const float* bhh = dir ? bhh_b : bhh_f;
    const unsigned short* Bsrc = Wb_ih + ((size_t)dir * NG + g0) * NE;
    const unsigned short* Asrc = ebf + (size_t)r0 * NE;

    f32x4 acc[4][4] = {};
#pragma unroll
    for (int ks = 0; ks < 4; ++ks) {
        int k0 = ks * 64;
#pragma unroll
        for (int i = 0; i < 4; ++i) {
            int rr = (w * 4 + i) * 8 + srow8;
            GL16(Asrc + (size_t)rr * NE + k0 + schunk * 8, Atile + (w * 4 + i) * 512);
            GL16(Bsrc + (size_t)rr * NE + k0 + schunk * 8, Btile + (w * 4 + i) * 512);
        }
        __syncthreads();   // drains staging (vmcnt) + LDS
        short8 a[4][2], b[4][2];
#pragma unroll
        for (int mi = 0; mi < 4; ++mi)
#pragma unroll
            for (int kk = 0; kk < 2; ++kk)
                a[mi][kk] = *(const short8*)&Atile[(wr * 64 + mi * 16 + lrow) * 64 + kk * 32 + kg * 8];
#pragma unroll
        for (int ni = 0; ni < 4; ++ni)
#pragma unroll
            for (int kk = 0; kk < 2; ++kk)
                b[ni][kk] = *(const short8*)&Btile[(wc * 64 + ni * 16 + lrow) * 64 + kk * 32 + kg * 8];
#pragma unroll
        for (int mi = 0; mi < 4; ++mi)
#pragma unroll
            for (int ni = 0; ni < 4; ++ni)
#pragma unroll
                for (int kk = 0; kk < 2; ++kk)
                    acc[mi][ni] = __builtin_amdgcn_mfma_f32_16x16x32_bf16(a[mi][kk], b[ni][kk], acc[mi][ni], 0, 0, 0);
        __syncthreads();   // all reads done before next restage
    }

#pragma unroll
    for (int ni = 0; ni < 4; ++ni) {
        int g = g0 + wc * 64 + ni * 16 + lrow;
        float bias = bih[g] + bhh[g];
#pragma unroll
        for (int mi = 0; mi < 4; ++mi) {
            int r = r0 + wr * 64 + mi * 16 + kg * 4;
            int t = r >> 9;
            int s = r & 511;
            int sb = s >> 4;
            unsigned short* dst = Xp + ((((size_t)dir * 32 + sb) * 32 + t) << 13) + g * 16 + (s & 15);
            unsigned o0 = f2bf(acc[mi][ni][0] + bias);
            unsigned o1 = f2bf(acc[mi][ni][1] + bias);
            unsigned o2 = f2bf(acc[mi][ni][2] + bias);
            unsigned o3 = f2bf(acc[mi][ni][3] + bias);
            uint2 pk; pk.x = o0 | (o1 << 16); pk.y = o2 | (o3 << 16);
            *(uint2*)dst = pk;
        }
    }
}

// ---------------- LSTM recurrence: in-register cell update, 1 barrier/step ----------------
// Wave w owns h-slice [w*16,w*16+16): gate fragments at g = q*128 + w*16 (+lrow).
// Lane holds gates i,f,g~,o for its own (s,h) -> epilogue fully in registers.
// h(t) -> double-buffered h_lds (bf16) + separate Hout[dir][sb][t][16s][128h].
__launch_bounds__(512, 2)
__global__ void k_lstm(const unsigned short* Wb_hh, const unsigned short* Xp,
                       unsigned short* Hout, const float* h0, const float* c0)
{
    __shared__ unsigned short h_lds[2][16 * 136];
    int dir = blockIdx.x >> 5;
    int sb = blockIdx.x & 31;
    int s0 = sb * 16;
    int tid = threadIdx.x;
    int w = tid >> 6, lane = tid & 63;
    int lrow = lane & 15, kg = lane >> 4;

    short8 bfr[4][4];
#pragma unroll
    for (int q = 0; q < 4; ++q) {
        const unsigned short* p = Wb_hh + ((size_t)dir * NG + (q * 128 + w * 16 + lrow)) * NH2 + kg * 8;
#pragma unroll
        for (int kf = 0; kf < 4; ++kf)
            bfr[q][kf] = *(const short8*)(p + kf * 32);
    }

    float c[4];
#pragma unroll
    for (int i = 0; i < 4; ++i)
        c[i] = c0[((size_t)dir * NS + s0 + kg * 4 + i) * NH2 + w * 16 + lrow];
    {
        int sl = tid >> 5, hq = tid & 31;
        f32x4 hv = *(const f32x4*)(h0 + ((size_t)dir * NS + s0 + sl) * NH2 + hq * 4);
        ushort4v hb; hb[0] = f2bf(hv[0]); hb[1] = f2bf(hv[1]); hb[2] = f2bf(hv[2]); hb[3] = f2bf(hv[3]);
        *(ushort4v*)&h_lds[0][sl * 136 + hq * 4] = hb;
    }

    const unsigned short* xbase = Xp + (((size_t)dir * 32 + sb) * 32) * 8192;
    unsigned short* hslot = Hout + (((size_t)dir * 32 + sb) * 32) * 2048;
    int xoff0 = (w * 16 + lrow) * 16 + kg * 4;     // q=0 gate offset within slot

    ushort4v xA[4], xB[4];
#pragma unroll
    for (int q = 0; q < 4; ++q)
        xA[q] = *(const ushort4v*)(xbase + (size_t)(dir ? 31 : 0) * 8192 + xoff0 + q * 2048);
#pragma unroll
    for (int q = 0; q < 4; ++q)
        xB[q] = *(const ushort4v*)(xbase + (size_t)(dir ? 30 : 1) * 8192 + xoff0 + q * 2048);
    __syncthreads();

#define LSTM_STEP(T, XV, PR, PW)                                                       \
    {                                                                                  \
        int tx = dir ? 31 - (T) : (T);                                                 \
        short8 afr[4];                                                                 \
        _Pragma("unroll")                                                              \
        for (int kf = 0; kf < 4; ++kf)                                                 \
            afr[kf] = *(const short8*)&h_lds[PR][lrow * 136 + kf * 32 + kg * 8];       \
        f32x4 acc[4] = {};                                                             \
        _Pragma("unroll")                                                              \
        for (int q = 0; q < 4; ++q)                                                    \
            _Pragma("unroll")                                                          \
            for (int kf = 0; kf < 4; ++kf)                                             \
                acc[q] = __builtin_amdgcn_mfma_f32_16x16x32_bf16(afr[kf], bfr[q][kf],  \
                                                                 acc[q], 0, 0, 0);     \
        float gs[4][4];                                                                \
        _Pragma("unroll")                                                              \
        for (int q = 0; q < 4; ++q)                                                    \
            _Pragma("unroll")                                                          \
            for (int i = 0; i < 4; ++i)                                                \
                gs[q][i] = acc[q][i] + bf2f(XV[q][i]);                                 \
        if ((T) + 2 < 32) {                                                            \
            int txn = dir ? 29 - (T) : (T) + 2;                                        \
            _Pragma("unroll")                                                          \
            for (int q = 0; q < 4; ++q)                                                \
                XV[q] = *(const ushort4v*)(xbase + (size_t)txn * 8192 + xoff0 + q * 2048); \
        }                                                                              \
        _Pragma("unroll")                                                              \
        for (int i = 0; i < 4; ++i) {                                                  \
            float ci = sigmoidf_(gs[1][i]) * c[i] + sigmoidf_(gs[0][i]) * tanhf_(gs[2][i]); \
            c[i] = ci;                                                                 \
            unsigned short hb = f2bf(sigmoidf_(gs[3][i]) * tanhf_(ci));                \
            h_lds[PW][(kg * 4 + i) * 136 + w * 16 + lrow] = hb;                        \
            hslot[(size_t)tx * 2048 + (kg * 4 + i) * 128 + w * 16 + lrow] = hb;        \
        }                                                                              \
        wg_barrier();                                                                  \
    }

    for (int tt = 0; tt < 16; ++tt) {
        LSTM_STEP(2 * tt,     xA, ((2 * tt) & 1),     (((2 * tt) & 1) ^ 1))
        LSTM_STEP(2 * tt + 1, xB, ((2 * tt + 1) & 1), (((2 * tt + 1) & 1) ^ 1))
    }
#undef LSTM_STEP
}

// ---------------- fused FC + CRF leaf/segment tree ----------------
__device__ __forceinline__ float mm_combine(const unsigned short* Rb, const unsigned short* Tb,
                                            int lane, f32x4 c[2][2])
{
    int lrow = lane & 15, kg = lane >> 4;
    short8 a0 = *(const short8*)(Rb + lrow * 32 + kg * 8);
    short8 a1 = *(const short8*)(Rb + (16 + lrow) * 32 + kg * 8);
    short8 b0 = *(const short8*)(Tb + lrow * 32 + kg * 8);
    short8 b1 = *(const short8*)(Tb + (16 + lrow) * 32 + kg * 8);
    c[0][0] = __builtin_amdgcn_mfma_f32_16x16x32_bf16(a0, b0, c[0][0], 0, 0, 0);
    c[0][1] = __builtin_amdgcn_mfma_f32_16x16x32_bf16(a0, b1, c[0][1], 0, 0, 0);
    c[1][0] = __builtin_amdgcn_mfma_f32_16x16x32_bf16(a1, b0, c[1][0], 0, 0, 0);
    c[1][1] = __builtin_amdgcn_mfma_f32_16x16x32_bf16(a1, b1, c[1][1], 0, 0, 0);
    float mx = 0.f;
#pragma unroll
    for (int ti = 0; ti < 2; ++ti)
#pragma unroll
        for (int tj = 0; tj < 2; ++tj)
#pragma unroll
            for (int i = 0; i < 4; ++i) mx = fmaxf(mx, c[ti][tj][i]);
#pragma unroll
    for (int off = 32; off; off >>= 1) mx = fmaxf(mx, __shfl_xor(mx, off));
    return fmaxf(mx, 1e-30f);
}

__device__ __forceinline__ void write_scaled(unsigned short* outp, bool Rlayout,
                                             int lane, const f32x4 c[2][2], float inv)
{
    int lrow = lane & 15, kg = lane >> 4;
    if (Rlayout) {
#pragma unroll
        for (int ti = 0; ti < 2; ++ti)
#pragma unroll
            for (int tj = 0; tj < 2; ++tj) {
                int cc = tj * 16 + lrow;
#pragma unroll
                for (int i = 0; i < 4; ++i) {
                    int r = ti * 16 + kg * 4 + i;
                    float v = (r < NT && cc < NT) ? c[ti][tj][i] * inv : 0.f;
                    outp[r * 32 + cc] = f2bf(v);
                }
            }
    } else {
#pragma unroll
        for (int ti = 0; ti < 2; ++ti)
#pragma unroll
            for (int tj = 0; tj < 2; ++tj) {
                int cc = tj * 16 + lrow;
                int r0 = ti * 16 + kg * 4;
                ushort4v pk;
#pragma unroll
                for (int i = 0; i < 4; ++i) {
                    int r = r0 + i;
                    float v = (r < NT && cc < NT) ? c[ti][tj][i] * inv : 0.f;
                    pk[i] = f2bf(v);
                }
                *(ushort4v*)(outp + cc * 32 + r0) = pk;
            }
    }
}

// block (b=LSTM step, seg=sb): FC (waves 0,1) -> feats+ef, then 16 leaves -> 1 seg matrix
__launch_bounds__(256)
__global__ void k_fcrf(const unsigned short* Hout, const unsigned short* fcpad,
                       const float* fcb, const float* trans,
                       float* feats, unsigned short* Mseg, float* lscseg)
{
    __shared__ unsigned short mats[16 * 1024];   // 32KB
    __shared__ float etR[484], etT[484];
    __shared__ float ef[16 * 24];
    __shared__ float lscm[16];
    __shared__ f32x4 part[2][64];
    int b = blockIdx.x, seg = blockIdx.y;
    int tid = threadIdx.x;
    int w = tid >> 6, lane = tid & 63;
    int lrow = lane & 15, kg = lane >> 4;

    f32x4 fa[2] = {};
    if (w < 2) {
        int dir = w;
        const unsigned short* hb = Hout + (((size_t)dir * 32 + seg) * 32 + b) * 2048 + lrow * 128 + kg * 8;
        const unsigned short* fb = fcpad + dir * 4096 + lrow * 128 + kg * 8;
#pragma unroll
        for (int kf = 0; kf < 4; ++kf) {
            short8 a  = *(const short8*)(hb + kf * 32);
            short8 b0 = *(const short8*)(fb + kf * 32);
            short8 b1 = *(const short8*)(fb + 2048 + kf * 32);
            fa[0] = __builtin_amdgcn_mfma_f32_16x16x32_bf16(a, b0, fa[0], 0, 0, 0);
            fa[1] = __builtin_amdgcn_mfma_f32_16x16x32_bf16(a, b1, fa[1], 0, 0, 0);
        }
        if (dir == 1) { part[0][lane] = fa[0]; part[1][lane] = fa[1]; }
        if (w == 1 && lane < 16) lscm[lane] = 0.f;
    } else {
        for (int i = tid - 128; i < 484; i += 128) {
            float e = __expf(trans[i]);
            etR[i] = e;
            etT[(i % NT) * NT + (i / NT)] = e;
        }
    }
    __syncthreads();
    if (w == 0) {
        fa[0] += part[0][lane];
        fa[1] += part[1][lane];
#pragma unroll
        for (int nf = 0; nf < 2; ++nf) {
            int tag = nf * 16 + lrow;
            if (tag < NT) {
                float bias = fcb[tag];
#pragma unroll
                for (int i = 0; i < 4; ++i) {
                    int s = kg * 4 + i;
                    float f = fa[nf][i] + bias;
                    feats[((size_t)b * NS + seg * 16 + s) * NT + tag] = f;
                    ef[s * 24 + tag] = __expf(f);
                }
            }
        }
    }
    __syncthreads();

    // build leaves: t odd -> R layout [j][k]; t even -> T layout [k][j]
    for (int idx = tid; idx < 16 * 1024; idx += 256) {
        int t = idx >> 10, cell = idx & 1023, row = cell >> 5, col = cell & 31;
        float v = 0.f;
        if (row < NT && col < NT) {
            v = (t & 1) ? etR[row * NT + col] * ef[t * 24 + row]
                        : etT[row * NT + col] * ef[t * 24 + col];
        }
        mats[idx] = f2bf(v);
    }
    __syncthreads();

    for (int lvl = 0; lvl < 4; ++lvl) {
        int nP = 8 >> lvl;
        for (int p = w; p < nP; p += 4) {
            int aslot = (2 * p) << lvl, bslot = (2 * p + 1) << lvl;
            f32x4 c[2][2] = {};
            float mx = mm_combine(mats + bslot * 1024, mats + aslot * 1024, lane, c);
            float inv = __builtin_amdgcn_rcpf(mx);
            float nlsc = lscm[aslot] + lscm[bslot] + __logf(mx);
            if (lvl < 3) {
                write_scaled(mats + aslot * 1024, (p & 1) != 0, lane, c, inv);
                if (lane == 0) lscm[aslot] = nlsc;
            } else {
                write_scaled(Mseg + ((size_t)b * 32 + seg) * 1024, (seg & 1) != 0, lane, c, inv);
                if (lane == 0) lscseg[b * 32 + seg] = nlsc;
            }
        }
        __syncthreads();
    }
}

__launch_bounds__(256)
__global__ void k_crf2(const unsigned short* Mseg, const float* lscseg,
                       const float* feats, const float* trans, const int* Y,
                       float* fwd_sc, float* gold_sc)
{
    __shared__ unsigned short mats[16 * 1024];
    __shared__ float lscm[16];
    __shared__ float tl[484];
    __shared__ float col20[32];
    __shared__ float red[4];
    int b = blockIdx.x;
    int tid = threadIdx.x;
    int w = tid >> 6, lane = tid & 63;
    int lrow = lane & 15, kg = lane >> 4;

    for (int i = tid; i < 484; i += 256) tl[i] = trans[i];
    __syncthreads();

    const unsigned short* base = Mseg + (size_t)b * 32 * 1024;
    for (int p = w; p < 16; p += 4) {
        f32x4 c[2][2] = {};
        float mx = mm_combine(base + (2 * p + 1) * 1024, base + (2 * p) * 1024, lane, c);
        float inv = __builtin_amdgcn_rcpf(mx);
        float nlsc = lscseg[b * 32 + 2 * p] + lscseg[b * 32 + 2 * p + 1] + __logf(mx);
        write_scaled(mats + p * 1024, (p & 1) != 0, lane, c, inv);
        if (lane == 0) lscm[p] = nlsc;
    }
    __syncthreads();

    for (int lvl = 0; lvl < 4; ++lvl) {
        int nP = 8 >> lvl;
        for (int p = w; p < nP; p += 4) {
            int aslot = (2 * p) << lvl, bslot = (2 * p + 1) << lvl;
            f32x4 c[2][2] = {};
            float mx = mm_combine(mats + bslot * 1024, mats + aslot * 1024, lane, c);
            if (lvl < 3) {
                float inv = __builtin_amdgcn_rcpf(mx);
                float nlsc = lscm[aslot] + lscm[bslot] + __logf(mx);
                write_scaled(mats + aslot * 1024, (p & 1) != 0, lane, c, inv);
                if (lane == 0) lscm[aslot] = nlsc;
            } else {
                if (lrow == 4) {
#pragma unroll
                    for (int ti = 0; ti < 2; ++ti)
#pragma unroll
                        for (int i = 0; i < 4; ++i)
                            col20[ti * 16 + kg * 4 + i] = c[ti][1][i];
                }
                if (lane == 0) lscm[0] = lscm[0] + lscm[8];
            }
        }
        __syncthreads();
    }

    if (w == 0) {
        float v = 0.f;
        if (lane < NT) v = __expf(tl[(NT - 1) * NT + lane]) * col20[lane];
#pragma unroll
        for (int off = 32; off; off >>= 1) v += __shfl_xor(v, off);
        if (lane == 0) fwd_sc[b] = __logf(v) + lscm[0];
    }

    const float* fb = feats + (size_t)b * NS * NT;
    float acc = 0.f;
    for (int s = tid; s < NS; s += 256) {
        int y = Y[b * NS + s];
        int yp = s ? Y[b * NS + s - 1] : (NT - 2);
        acc += fb[s * NT + y] + tl[y * NT + yp];
    }
    if (tid == 0) acc += tl[(NT - 1) * NT + Y[b * NS + NS - 1]];
#pragma unroll
    for (int off = 32; off; off >>= 1) acc += __shfl_xor(acc, off);
    if (lane == 0) red[w] = acc;
    __syncthreads();
    if (tid == 0) gold_sc[b] = red[0] + red[1] + red[2] + red[3];
}

// ---------------- final: score ----------------
__global__ void k_final(const float* fwd_sc, const float* gold_sc, float* out)
{
    float v = (threadIdx.x < NB) ? (fwd_sc[threadIdx.x] - gold_sc[threadIdx.x]) : 0.f;
#pragma unroll
    for (int off = 32; off; off >>= 1) v += __shfl_xor(v, off);
    if (threadIdx.x == 0) out[0] = v * (1.f / NB);
}

extern "C" void kernel_launch(void* const* d_in, const int* in_sizes, int n_in,
                              void* d_out, int out_size, void* d_ws, size_t ws_size,
                              hipStream_t stream)
{
    const int* X = (const int*)d_in[0];
    const int* Y = (const int*)d_in[1];
    const float* emb = (const float*)d_in[2];
    const float* Wih_f = (const float*)d_in[3];
    const float* Whh_f = (const float*)d_in[4];
    const float* bih_f = (const float*)d_in[5];
    const float* bhh_f = (const float*)d_in[6];
    const float* Wih_b = (const float*)d_in[7];
    const float* Whh_b = (const float*)d_in[8];
    const float* bih_b = (const float*)d_in[9];
    const float* bhh_b = (const float*)d_in[10];
    const float* fcW = (const float*)d_in[11];
    const float* fcb = (const float*)d_in[12];
    const float* trans = (const float*)d_in[13];
    const float* h0 = (const float*)d_in[14];
    const float* c0 = (const float*)d_in[15];
    float* out = (float*)d_out;

    char* ws = (char*)d_ws;
    unsigned short* Wb_ih = (unsigned short*)(ws + 0);          // 524288 B
    unsigned short* Wb_hh = (unsigned short*)(ws + 524288);     // 262144 B
    unsigned short* fcpad = (unsigned short*)(ws + 786432);     // 16384 B
    unsigned short* Xp    = (unsigned short*)(ws + 802816);     // 33554432 B
    float* feats          = (float*)(ws + 34357248);            // 1441792 B
    float* fwd_sc         = (float*)(ws + 35799040);            // 128 B
    float* gold_sc        = (float*)(ws + 35799168);            // 128 B
    unsigned short* ebf   = (unsigned short*)(ws + 35799296);   // 8388608 B
    unsigned short* Mseg  = ebf;                                // 2097152 B (ebf dead after k_xproj)
    float* lscseg         = (float*)(ws + 35799296 + 2097152);  // 4096 B
    unsigned short* Hout  = (unsigned short*)(ws + 44187904);   // 16777216 B (total ~61 MB)

    k_pre<<<dim3(5728), dim3(256), 0, stream>>>(X, emb, Y, Wih_f, Wih_b, Whh_f, Whh_b,
                                                fcW, ebf, Wb_ih, Wb_hh, fcpad, out);
    k_xproj<<<dim3(128, 4, 2), dim3(256), 0, stream>>>(ebf, Wb_ih, bih_f, bhh_f, bih_b, bhh_b, Xp);
    k_lstm<<<dim3(64), dim3(512), 0, stream>>>(Wb_hh, Xp, Hout, h0, c0);
    k_fcrf<<<dim3(32, 32), dim3(256), 0, stream>>>(Hout, fcpad, fcb, trans, feats, Mseg, lscseg);
    k_crf2<<<dim3(NB), dim3(256), 0, stream>>>(Mseg, lscseg, feats, trans, Y, fwd_sc, gold_sc);
    k_final<<<dim3(1), dim3(64), 0, stream>>>(fwd_sc, gold_sc, out);
    (void)in_sizes; (void)n_in; (void)out_size; (void)ws_size;
}